// Round 3
// baseline (158.181 us; speedup 1.0000x reference)
//
#include <hip/hip_runtime.h>
#include <stdint.h>

#define Td 1024
#define Hd 1024
#define Id 1024
#define Ed 8
#define Kd 2
#define Ld 4
#define Rd 16
#define Nd 2048
#define TKd (Td*Kd)

typedef __bf16 bf16x8 __attribute__((ext_vector_type(8)));
typedef float f32x4 __attribute__((ext_vector_type(4)));

__device__ __forceinline__ ushort f2bf(float f) {
    uint32_t u = __builtin_bit_cast(uint32_t, f);
    return (ushort)((u + 0x7fffu + ((u >> 16) & 1u)) >> 16);
}
__device__ __forceinline__ float bf2f(ushort u) {
    uint32_t x = ((uint32_t)u) << 16;
    return __builtin_bit_cast(float, x);
}
__device__ __forceinline__ bf16x8 pack8(float4 a, float4 b) {
    bf16x8 r;
    r[0] = (__bf16)a.x; r[1] = (__bf16)a.y; r[2] = (__bf16)a.z; r[3] = (__bf16)a.w;
    r[4] = (__bf16)b.x; r[5] = (__bf16)b.y; r[6] = (__bf16)b.z; r[7] = (__bf16)b.w;
    return r;
}

#define GLOAD_LDS16(g, l) __builtin_amdgcn_global_load_lds( \
    (const __attribute__((address_space(1))) uint32_t*)(const void*)(g), \
    (__attribute__((address_space(3))) uint32_t*)(void*)(l), 16, 0, 0)

// ---------------- route sort: bucket pairs by expert ----------------
__global__ void k_route(const int* __restrict__ topk_ids, int* __restrict__ sorted,
                        int* __restrict__ offs) {
    __shared__ int cnt[Ed];
    __shared__ int cur[Ed];
    int tid = threadIdx.x;            // 1024 threads, 2 pairs each
    if (tid < Ed) cnt[tid] = 0;
    __syncthreads();
    int e0 = topk_ids[tid];
    int e1 = topk_ids[tid + 1024];
    atomicAdd(&cnt[e0], 1);
    atomicAdd(&cnt[e1], 1);
    __syncthreads();
    if (tid == 0) {
        int s = 0;
        for (int e = 0; e < Ed; ++e) { offs[e] = s; cur[e] = s; s += cnt[e]; }
        offs[Ed] = s;
    }
    __syncthreads();
    int pos = atomicAdd(&cur[e0], 1);
    sorted[pos] = tid;
    pos = atomicAdd(&cur[e1], 1);
    sorted[pos] = tid + 1024;
}

// ---------------- persistent grouped GEMM ----------------
// C[p, 0:NC] = A[row(p), 0:1024] @ B[e][0:NC][0:1024]^T   (K = 1024, BK = 32)
// BM = 64 rows/tile, BN cols/tile. 4 waves in 2x2 quadrants: wave = 32 x (BN/2).
// AFP32: A = fp32 hidden gathered via sorted[]>>1 (reg-staged + cvt).
// else : A = bf16 act gathered via sorted[] (global_load_lds direct).
// B is fp32 weights, reg-staged + cvt. Double-buffered LDS, 1 barrier/K-step.
template<int NC, int BN, bool AFP32>
__global__ __launch_bounds__(256) void k_gemm3(
    const void* __restrict__ Asrc, const float* __restrict__ Bw,
    float* __restrict__ C, const int* __restrict__ sorted,
    const int* __restrict__ offs)
{
    constexpr int BM = 64;
    constexpr int NTN = NC / BN;          // n-tiles (power of 2)
    constexpr int NREP = BN / 32;         // B frags per wave
    constexpr int LOG_NTN = (NTN == 16) ? 4 : ((NTN == 8) ? 3 : 5);

    __shared__ ushort As[2][BM][32];
    __shared__ ushort Bs[2][BN][32];

    const int tid = threadIdx.x;
    const int lane = tid & 63;
    const int wave = tid >> 6;
    const int wr = wave >> 1, wc = wave & 1;
    const int fr = lane & 15;
    const int fk = (lane >> 4) * 8;

    int off[Ed + 1];
    #pragma unroll
    for (int e = 0; e <= Ed; ++e) off[e] = offs[e];
    int mt[Ed]; int tot = 0;
    #pragma unroll
    for (int e = 0; e < Ed; ++e) {
        int c = off[e + 1] - off[e];
        mt[e] = (c + BM - 1) / BM;
        tot += mt[e] * NTN;
    }

    for (int tau = blockIdx.x; tau < tot; tau += gridDim.x) {
        // decode tile -> (expert, m0, n0)
        int t = tau, e = 0;
        while (t >= mt[e] * NTN) { t -= mt[e] * NTN; ++e; }
        const int m0 = off[e] + (t >> LOG_NTN) * BM;
        const int mend = off[e + 1];
        const int n0 = (t & (NTN - 1)) * BN;

        // ---- per-thread staging addresses ----
        // A: row = tid>>2, k-chunk = (tid&3)*8 (8 elems, 16B bf16)
        const int arow = tid >> 2;
        const int akc = (tid & 3) * 8;
        int aIdx = m0 + arow; if (aIdx > mend - 1) aIdx = mend - 1;
        const int p_a = sorted[aIdx];
        const float*  af32 = (const float*)Asrc  + (size_t)(p_a >> 1) * 1024 + akc;
        const ushort* ab16 = (const ushort*)Asrc + (size_t)p_a * 1024 + akc;

        // B: BN=128 -> row=tid>>1, 16 elems; BN=64 -> row=tid>>2, 8 elems
        const int brow = (BN == 128) ? (tid >> 1) : (tid >> 2);
        const int bks  = (BN == 128) ? ((tid & 1) * 16) : ((tid & 3) * 8);
        const float* bsrc = Bw + ((size_t)e * NC + n0 + brow) * 1024 + bks;

        f32x4 acc[2][NREP] = {};

        // ---- prologue: stage k0 = 0 into buf 0 ----
        {
            if (AFP32) {
                float4 x0 = *(const float4*)(af32);
                float4 x1 = *(const float4*)(af32 + 4);
                *(bf16x8*)(&As[0][arow][akc]) = pack8(x0, x1);
            } else {
                GLOAD_LDS16(ab16, (char*)&As[0][0][0] + wave * 1024);
            }
            if (BN == 128) {
                float4 y0 = *(const float4*)(bsrc);
                float4 y1 = *(const float4*)(bsrc + 4);
                float4 y2 = *(const float4*)(bsrc + 8);
                float4 y3 = *(const float4*)(bsrc + 12);
                *(bf16x8*)(&Bs[0][brow][bks])     = pack8(y0, y1);
                *(bf16x8*)(&Bs[0][brow][bks + 8]) = pack8(y2, y3);
            } else {
                float4 y0 = *(const float4*)(bsrc);
                float4 y1 = *(const float4*)(bsrc + 4);
                *(bf16x8*)(&Bs[0][brow][bks]) = pack8(y0, y1);
            }
        }
        asm volatile("s_waitcnt vmcnt(0)" ::: "memory");
        __syncthreads();

        int buf = 0;
        for (int k0 = 32; k0 < 1024; k0 += 32) {
            // ---- issue next-tile loads (T14: issue early, write late) ----
            float4 x0, x1, y0, y1, y2, y3;
            if (AFP32) {
                x0 = *(const float4*)(af32 + k0);
                x1 = *(const float4*)(af32 + k0 + 4);
            } else {
                GLOAD_LDS16(ab16 + k0, (char*)&As[buf ^ 1][0][0] + wave * 1024);
            }
            y0 = *(const float4*)(bsrc + k0);
            y1 = *(const float4*)(bsrc + k0 + 4);
            if (BN == 128) {
                y2 = *(const float4*)(bsrc + k0 + 8);
                y3 = *(const float4*)(bsrc + k0 + 12);
            }

            // ---- compute current buffer ----
            bf16x8 afr[2], bfr[NREP];
            #pragma unroll
            for (int mi = 0; mi < 2; ++mi)
                afr[mi] = *(const bf16x8*)(&As[buf][wr * 32 + mi * 16 + fr][fk]);
            #pragma unroll
            for (int ni = 0; ni < NREP; ++ni)
                bfr[ni] = *(const bf16x8*)(&Bs[buf][wc * (BN / 2) + ni * 16 + fr][fk]);
            #pragma unroll
            for (int mi = 0; mi < 2; ++mi)
                #pragma unroll
                for (int ni = 0; ni < NREP; ++ni)
                    acc[mi][ni] = __builtin_amdgcn_mfma_f32_16x16x32_bf16(
                        afr[mi], bfr[ni], acc[mi][ni], 0, 0, 0);

            // ---- cvt + LDS write into next buffer ----
            if (AFP32)
                *(bf16x8*)(&As[buf ^ 1][arow][akc]) = pack8(x0, x1);
            if (BN == 128) {
                *(bf16x8*)(&Bs[buf ^ 1][brow][bks])     = pack8(y0, y1);
                *(bf16x8*)(&Bs[buf ^ 1][brow][bks + 8]) = pack8(y2, y3);
            } else {
                *(bf16x8*)(&Bs[buf ^ 1][brow][bks]) = pack8(y0, y1);
            }

            asm volatile("s_waitcnt vmcnt(0)" ::: "memory");
            __syncthreads();
            buf ^= 1;
        }
        // ---- final compute ----
        {
            bf16x8 afr[2], bfr[NREP];
            #pragma unroll
            for (int mi = 0; mi < 2; ++mi)
                afr[mi] = *(const bf16x8*)(&As[buf][wr * 32 + mi * 16 + fr][fk]);
            #pragma unroll
            for (int ni = 0; ni < NREP; ++ni)
                bfr[ni] = *(const bf16x8*)(&Bs[buf][wc * (BN / 2) + ni * 16 + fr][fk]);
            #pragma unroll
            for (int mi = 0; mi < 2; ++mi)
                #pragma unroll
                for (int ni = 0; ni < NREP; ++ni)
                    acc[mi][ni] = __builtin_amdgcn_mfma_f32_16x16x32_bf16(
                        afr[mi], bfr[ni], acc[mi][ni], 0, 0, 0);
        }

        // ---- epilogue: D layout col=lane&15 (n), row=(lane>>4)*4+j (m) ----
        const int rb = wr * 32 + (lane >> 4) * 4;
        #pragma unroll
        for (int mi = 0; mi < 2; ++mi) {
            #pragma unroll
            for (int j = 0; j < 4; ++j) {
                int sidx = m0 + rb + mi * 16 + j;
                if (sidx < mend) {
                    int p = sorted[sidx];
                    float* cr = C + (size_t)p * NC + n0 + wc * (BN / 2) + fr;
                    #pragma unroll
                    for (int ni = 0; ni < NREP; ++ni)
                        cr[ni * 16] = acc[mi][ni][j];
                }
            }
        }
        __syncthreads();   // protect LDS reuse across tile loop
    }
}

// ---------------- fused gate_up LoRA + silu_and_mul -> bf16 act ----------------
// act[p, i] = silu(c1[p,i] + s*Bg_i.tmp) * (c1[p,I+i] + s*Bg_{I+i}.tmp),  tmp = Ag @ x[t]
__global__ __launch_bounds__(256) void k_lsilu(
    const float* __restrict__ hid, const float* __restrict__ Ag,
    const float* __restrict__ Bg, const float* __restrict__ scal,
    const int* __restrict__ topk_ids, const int* __restrict__ lidx,
    const float* __restrict__ cache1, ushort* __restrict__ act)
{
    const int p = blockIdx.x;
    const int t = p >> 1;
    const int e = topk_ids[p];
    const int l = lidx[t];
    const float s = scal[l];
    __shared__ float tmp[Rd];

    const int tid = threadIdx.x, lane = tid & 63, wave = tid >> 6;
    const int r = wave * 4 + (lane >> 4);
    const int hl = lane & 15;
    const float* arow = Ag + (((size_t)l * Ed + e) * Rd + r) * Hd;
    const float* xr = hid + (size_t)t * Hd;
    float a = 0.f;
    for (int h0 = hl * 4; h0 < Hd; h0 += 64) {
        float4 av = *reinterpret_cast<const float4*>(&arow[h0]);
        float4 xv = *reinterpret_cast<const float4*>(&xr[h0]);
        a += av.x * xv.x + av.y * xv.y + av.z * xv.z + av.w * xv.w;
    }
    a += __shfl_xor(a, 1); a += __shfl_xor(a, 2);
    a += __shfl_xor(a, 4); a += __shfl_xor(a, 8);
    if (hl == 0) tmp[r] = a;
    __syncthreads();

    float tl[Rd];
    #pragma unroll
    for (int q = 0; q < Rd; ++q) tl[q] = tmp[q];
    const float* Bbase = Bg + ((size_t)l * Ed + e) * Nd * Rd;
    const float* c1r = cache1 + (size_t)p * Nd;
    ushort* actr = act + (size_t)p * Id;
    #pragma unroll
    for (int ii = 0; ii < Id / 256; ++ii) {
        int i = ii * 256 + tid;
        const float4* bg = reinterpret_cast<const float4*>(Bbase + (size_t)i * Rd);
        const float4* bu = reinterpret_cast<const float4*>(Bbase + (size_t)(Id + i) * Rd);
        float4 g0 = bg[0], g1 = bg[1], g2 = bg[2], g3 = bg[3];
        float4 u0 = bu[0], u1 = bu[1], u2 = bu[2], u3 = bu[3];
        float dg = g0.x*tl[0]+g0.y*tl[1]+g0.z*tl[2]+g0.w*tl[3]
                 + g1.x*tl[4]+g1.y*tl[5]+g1.z*tl[6]+g1.w*tl[7]
                 + g2.x*tl[8]+g2.y*tl[9]+g2.z*tl[10]+g2.w*tl[11]
                 + g3.x*tl[12]+g3.y*tl[13]+g3.z*tl[14]+g3.w*tl[15];
        float du = u0.x*tl[0]+u0.y*tl[1]+u0.z*tl[2]+u0.w*tl[3]
                 + u1.x*tl[4]+u1.y*tl[5]+u1.z*tl[6]+u1.w*tl[7]
                 + u2.x*tl[8]+u2.y*tl[9]+u2.z*tl[10]+u2.w*tl[11]
                 + u3.x*tl[12]+u3.y*tl[13]+u3.z*tl[14]+u3.w*tl[15];
        float gate = c1r[i] + dg * s;
        float up   = c1r[Id + i] + du * s;
        float v = gate / (1.f + __expf(-gate)) * up;
        actr[i] = f2bf(v);
    }
}

// ---------------- fused down LoRA + routed-weight moe_sum ----------------
// out[t,h] = sum_k w_k * ( cache3[p_k,h] + s * Bd_h . tmpd_k ),  tmpd_k = Ad @ act[p_k]
__global__ __launch_bounds__(256) void k_dfinal(
    const ushort* __restrict__ act, const float* __restrict__ Ad,
    const float* __restrict__ Bd, const float* __restrict__ scal,
    const int* __restrict__ topk_ids, const int* __restrict__ lidx,
    const float* __restrict__ tw, const float* __restrict__ cache3,
    float* __restrict__ out)
{
    const int t = blockIdx.x;
    const int l = lidx[t];
    const float s = scal[l];
    const int e0 = topk_ids[t * 2], e1 = topk_ids[t * 2 + 1];
    const float w0 = tw[t * 2], w1 = tw[t * 2 + 1];
    __shared__ float tmp[2][Rd];

    const int tid = threadIdx.x, lane = tid & 63, wave = tid >> 6;
    const int r = wave * 4 + (lane >> 4);
    const int hl = lane & 15;
    #pragma unroll
    for (int k = 0; k < 2; ++k) {
        const int e = k ? e1 : e0;
        const float* arow = Ad + (((size_t)l * Ed + e) * Rd + r) * Id;
        const ushort* xr = act + (size_t)(t * 2 + k) * Id;
        float a = 0.f;
        for (int h0 = hl * 4; h0 < Id; h0 += 64) {
            float4 av = *reinterpret_cast<const float4*>(&arow[h0]);
            ushort4 xv = *reinterpret_cast<const ushort4*>(&xr[h0]);
            a += av.x * bf2f(xv.x) + av.y * bf2f(xv.y) + av.z * bf2f(xv.z) + av.w * bf2f(xv.w);
        }
        a += __shfl_xor(a, 1); a += __shfl_xor(a, 2);
        a += __shfl_xor(a, 4); a += __shfl_xor(a, 8);
        if (hl == 0) tmp[k][r] = a;
    }
    __syncthreads();

    float t0[Rd], t1[Rd];
    #pragma unroll
    for (int q = 0; q < Rd; ++q) { t0[q] = tmp[0][q]; t1[q] = tmp[1][q]; }
    const float* B0 = Bd + ((size_t)l * Ed + e0) * Hd * Rd;
    const float* B1 = Bd + ((size_t)l * Ed + e1) * Hd * Rd;
    const float* c30 = cache3 + (size_t)(t * 2) * Hd;
    const float* c31 = cache3 + (size_t)(t * 2 + 1) * Hd;
    float* outr = out + (size_t)t * Hd;
    #pragma unroll
    for (int hh = 0; hh < Hd / 256; ++hh) {
        int h = hh * 256 + tid;
        const float4* b0 = reinterpret_cast<const float4*>(B0 + (size_t)h * Rd);
        const float4* b1 = reinterpret_cast<const float4*>(B1 + (size_t)h * Rd);
        float4 a0 = b0[0], a1 = b0[1], a2 = b0[2], a3 = b0[3];
        float4 c0 = b1[0], c1 = b1[1], c2 = b1[2], c3 = b1[3];
        float d0 = a0.x*t0[0]+a0.y*t0[1]+a0.z*t0[2]+a0.w*t0[3]
                 + a1.x*t0[4]+a1.y*t0[5]+a1.z*t0[6]+a1.w*t0[7]
                 + a2.x*t0[8]+a2.y*t0[9]+a2.z*t0[10]+a2.w*t0[11]
                 + a3.x*t0[12]+a3.y*t0[13]+a3.z*t0[14]+a3.w*t0[15];
        float d1 = c0.x*t1[0]+c0.y*t1[1]+c0.z*t1[2]+c0.w*t1[3]
                 + c1.x*t1[4]+c1.y*t1[5]+c1.z*t1[6]+c1.w*t1[7]
                 + c2.x*t1[8]+c2.y*t1[9]+c2.z*t1[10]+c2.w*t1[11]
                 + c3.x*t1[12]+c3.y*t1[13]+c3.z*t1[14]+c3.w*t1[15];
        outr[h] = w0 * (c30[h] + s * d0) + w1 * (c31[h] + s * d1);
    }
}

extern "C" void kernel_launch(void* const* d_in, const int* in_sizes, int n_in,
                              void* d_out, int out_size, void* d_ws, size_t ws_size,
                              hipStream_t stream) {
    const float* hid  = (const float*)d_in[0];
    const float* tw   = (const float*)d_in[1];
    const float* w13  = (const float*)d_in[2];
    const float* w2   = (const float*)d_in[3];
    const float* ga   = (const float*)d_in[4];
    const float* gb   = (const float*)d_in[5];
    const float* da   = (const float*)d_in[6];
    const float* db   = (const float*)d_in[7];
    const float* sc   = (const float*)d_in[8];
    const int*   tids = (const int*)d_in[9];
    const int*   lidx = (const int*)d_in[10];
    float* out = (float*)d_out;

    char* ws = (char*)d_ws;
    float*  cache1 = (float*)(ws);                          // 16 MB
    ushort* act    = (ushort*)(ws + (16ull << 20));         // 4 MB
    float*  cache3 = (float*)(ws + (20ull << 20));          // 8 MB
    int*    sorted = (int*)(ws + (28ull << 20));            // 8 KB
    int*    offs   = (int*)(ws + (28ull << 20) + TKd * 4);  // 36 B

    k_route<<<1, 1024, 0, stream>>>(tids, sorted, offs);
    k_gemm3<Nd, 128, true><<<512, 256, 0, stream>>>(hid, w13, cache1, sorted, offs);
    k_lsilu<<<TKd, 256, 0, stream>>>(hid, ga, gb, sc, tids, lidx, cache1, act);
    k_gemm3<Hd, 64, false><<<512, 256, 0, stream>>>(act, w2, cache3, sorted, offs);
    k_dfinal<<<Td, 256, 0, stream>>>(act, da, db, sc, tids, lidx, tw, cache3, out);
}

// Round 4
// 143.016 us; speedup vs baseline: 1.1060x; 1.1060x over previous
//
#include <hip/hip_runtime.h>
#include <stdint.h>

#define Td 1024
#define Hd 1024
#define Id 1024
#define Ed 8
#define Kd 2
#define Ld 4
#define Rd 16
#define Nd 2048
#define TKd (Td*Kd)

typedef __bf16 bf16x8 __attribute__((ext_vector_type(8)));
typedef float f32x4 __attribute__((ext_vector_type(4)));

__device__ __forceinline__ ushort f2bf(float f) {
    uint32_t u = __builtin_bit_cast(uint32_t, f);
    return (ushort)((u + 0x7fffu + ((u >> 16) & 1u)) >> 16);
}
__device__ __forceinline__ float bf2f(ushort u) {
    uint32_t x = ((uint32_t)u) << 16;
    return __builtin_bit_cast(float, x);
}

#define GLOAD_LDS16(g, l) __builtin_amdgcn_global_load_lds( \
    (const __attribute__((address_space(1))) uint32_t*)(const void*)(g), \
    (__attribute__((address_space(3))) uint32_t*)(void*)(l), 16, 0, 0)

// ---------------- convert x + w13 + w2 fp32 -> bf16 (one kernel) ----------------
__global__ void k_convert(const float* __restrict__ x, const float* __restrict__ w13,
                          const float* __restrict__ w2, ushort* __restrict__ xb,
                          ushort* __restrict__ w13b, ushort* __restrict__ w2b) {
    constexpr int X8   = Td * Hd / 8;
    constexpr int W138 = Ed * Nd * Hd / 8;
    int i = blockIdx.x * blockDim.x + threadIdx.x;     // 8 floats per thread
    const float* src; ushort* dst; size_t off;
    if (i < X8)              { src = x;   dst = xb;   off = (size_t)i * 8; }
    else if (i < X8 + W138)  { src = w13; dst = w13b; off = (size_t)(i - X8) * 8; }
    else                     { src = w2;  dst = w2b;  off = (size_t)(i - X8 - W138) * 8; }
    float4 a = *reinterpret_cast<const float4*>(src + off);
    float4 b = *reinterpret_cast<const float4*>(src + off + 4);
    uint4 o;
    o.x = (uint)f2bf(a.x) | ((uint)f2bf(a.y) << 16);
    o.y = (uint)f2bf(a.z) | ((uint)f2bf(a.w) << 16);
    o.z = (uint)f2bf(b.x) | ((uint)f2bf(b.y) << 16);
    o.w = (uint)f2bf(b.z) | ((uint)f2bf(b.w) << 16);
    *reinterpret_cast<uint4*>(dst + off) = o;
}

// ---------------- route sort: bucket pairs by expert ----------------
__global__ void k_route(const int* __restrict__ topk_ids, int* __restrict__ sorted,
                        int* __restrict__ offs) {
    __shared__ int cnt[Ed];
    __shared__ int cur[Ed];
    int tid = threadIdx.x;
    if (tid < Ed) cnt[tid] = 0;
    __syncthreads();
    int e0 = topk_ids[tid];
    int e1 = topk_ids[tid + 1024];
    atomicAdd(&cnt[e0], 1);
    atomicAdd(&cnt[e1], 1);
    __syncthreads();
    if (tid == 0) {
        int s = 0;
        for (int e = 0; e < Ed; ++e) { offs[e] = s; cur[e] = s; s += cnt[e]; }
        offs[Ed] = s;
    }
    __syncthreads();
    int pos = atomicAdd(&cur[e0], 1);
    sorted[pos] = tid;
    pos = atomicAdd(&cur[e1], 1);
    sorted[pos] = tid + 1024;
}

// ---------------- grouped GEMM, m97 structure, persistent tile decode ----------------
// C[p, n] = sum_k A[row(p), k] * B[e][n, k];  K=1024, BK=32, all bf16 in LDS.
// 4 waves 2x2: wave owns (BM/2) x (BN/2); MREP x NREP frags of 16x16x32.
template<int NC, int BM, int BN, bool ROWDIV>
__global__ __launch_bounds__(256) void k_gemm4(
    const ushort* __restrict__ Ab, const ushort* __restrict__ Bb,
    float* __restrict__ C, const int* __restrict__ sorted,
    const int* __restrict__ offs)
{
    constexpr int NTN = NC / BN;            // n-tiles; 16 for both instantiations
    constexpr int MREP = BM / 32;
    constexpr int NREP = BN / 32;
    constexpr int RA = BM * 4 / 256;        // A staging rounds (16B chunks / 256 thr)
    constexpr int RB = BN * 4 / 256;

    __shared__ ushort As[BM][32];
    __shared__ ushort Bs[BN][32];

    const int tid = threadIdx.x;
    const int lane = tid & 63;
    const int wave = tid >> 6;
    const int wr = wave >> 1, wc = wave & 1;
    const int fr = lane & 15;
    const int fk = (lane >> 4) * 8;

    int off[Ed + 1];
    #pragma unroll
    for (int e = 0; e <= Ed; ++e) off[e] = offs[e];
    int mt[Ed]; int tot = 0;
    #pragma unroll
    for (int e = 0; e < Ed; ++e) {
        mt[e] = (off[e + 1] - off[e] + BM - 1) / BM;
        tot += mt[e] * NTN;
    }

    for (int tau = blockIdx.x; tau < tot; tau += gridDim.x) {
        int t = tau, e = 0;
        while (t >= mt[e] * NTN) { t -= mt[e] * NTN; ++e; }
        const int m0 = off[e] + (t >> 4) * BM;
        const int mend = off[e + 1];
        const int n0 = (t & 15) * BN;

        // per-thread staging sources (16B chunks): chunk c -> row c>>2, kchunk c&3
        const ushort* asrc[RA];
        #pragma unroll
        for (int r = 0; r < RA; ++r) {
            int c = r * 256 + tid;
            int row = c >> 2, kc = c & 3;
            int aIdx = m0 + row; if (aIdx > mend - 1) aIdx = mend - 1;
            int p = sorted[aIdx];
            int ar = ROWDIV ? (p >> 1) : p;
            asrc[r] = Ab + (size_t)ar * 1024 + kc * 8;
        }
        const ushort* bsrc[RB];
        #pragma unroll
        for (int r = 0; r < RB; ++r) {
            int c = r * 256 + tid;
            int row = c >> 2, kc = c & 3;
            bsrc[r] = Bb + ((size_t)e * NC + n0 + row) * 1024 + kc * 8;
        }

        f32x4 acc[MREP][NREP] = {};

        for (int k0 = 0; k0 < 1024; k0 += 32) {
            #pragma unroll
            for (int r = 0; r < RA; ++r)
                GLOAD_LDS16(asrc[r] + k0, (char*)&As[0][0] + (r * 256 + wave * 64) * 16);
            #pragma unroll
            for (int r = 0; r < RB; ++r)
                GLOAD_LDS16(bsrc[r] + k0, (char*)&Bs[0][0] + (r * 256 + wave * 64) * 16);

            __syncthreads();          // compiler emits vmcnt/lgkm drain before barrier

            bf16x8 af[MREP], bfv[NREP];
            #pragma unroll
            for (int mi = 0; mi < MREP; ++mi)
                af[mi] = *(const bf16x8*)(&As[wr * (BM / 2) + mi * 16 + fr][fk]);
            #pragma unroll
            for (int ni = 0; ni < NREP; ++ni)
                bfv[ni] = *(const bf16x8*)(&Bs[wc * (BN / 2) + ni * 16 + fr][fk]);
            #pragma unroll
            for (int mi = 0; mi < MREP; ++mi)
                #pragma unroll
                for (int ni = 0; ni < NREP; ++ni)
                    acc[mi][ni] = __builtin_amdgcn_mfma_f32_16x16x32_bf16(
                        af[mi], bfv[ni], acc[mi][ni], 0, 0, 0);

            __syncthreads();          // protect LDS for next K-step
        }

        // epilogue: D layout col=lane&15 (n), row=(lane>>4)*4+j (m)
        const int rb = wr * (BM / 2) + (lane >> 4) * 4;
        #pragma unroll
        for (int mi = 0; mi < MREP; ++mi) {
            #pragma unroll
            for (int j = 0; j < 4; ++j) {
                int sidx = m0 + rb + mi * 16 + j;
                if (sidx < mend) {
                    int p = sorted[sidx];
                    float* cr = C + (size_t)p * NC + n0 + wc * (BN / 2) + fr;
                    #pragma unroll
                    for (int ni = 0; ni < NREP; ++ni)
                        cr[ni * 16] = acc[mi][ni][j];
                }
            }
        }
    }
}

// ---------------- fused gate_up LoRA + silu_and_mul -> bf16 act ----------------
__global__ __launch_bounds__(256) void k_lsilu(
    const float* __restrict__ hid, const float* __restrict__ Ag,
    const float* __restrict__ Bg, const float* __restrict__ scal,
    const int* __restrict__ topk_ids, const int* __restrict__ lidx,
    const float* __restrict__ cache1, ushort* __restrict__ act)
{
    const int p = blockIdx.x;
    const int t = p >> 1;
    const int e = topk_ids[p];
    const int l = lidx[t];
    const float s = scal[l];
    __shared__ float tmp[Rd];

    const int tid = threadIdx.x, lane = tid & 63, wave = tid >> 6;
    const int r = wave * 4 + (lane >> 4);
    const int hl = lane & 15;
    const float* arow = Ag + (((size_t)l * Ed + e) * Rd + r) * Hd;
    const float* xr = hid + (size_t)t * Hd;
    float a = 0.f;
    for (int h0 = hl * 4; h0 < Hd; h0 += 64) {
        float4 av = *reinterpret_cast<const float4*>(&arow[h0]);
        float4 xv = *reinterpret_cast<const float4*>(&xr[h0]);
        a += av.x * xv.x + av.y * xv.y + av.z * xv.z + av.w * xv.w;
    }
    a += __shfl_xor(a, 1); a += __shfl_xor(a, 2);
    a += __shfl_xor(a, 4); a += __shfl_xor(a, 8);
    if (hl == 0) tmp[r] = a;
    __syncthreads();

    float tl[Rd];
    #pragma unroll
    for (int q = 0; q < Rd; ++q) tl[q] = tmp[q];
    const float* Bbase = Bg + ((size_t)l * Ed + e) * Nd * Rd;
    const float* c1r = cache1 + (size_t)p * Nd;
    ushort* actr = act + (size_t)p * Id;
    #pragma unroll
    for (int ii = 0; ii < Id / 256; ++ii) {
        int i = ii * 256 + tid;
        const float4* bg = reinterpret_cast<const float4*>(Bbase + (size_t)i * Rd);
        const float4* bu = reinterpret_cast<const float4*>(Bbase + (size_t)(Id + i) * Rd);
        float4 g0 = bg[0], g1 = bg[1], g2 = bg[2], g3 = bg[3];
        float4 u0 = bu[0], u1 = bu[1], u2 = bu[2], u3 = bu[3];
        float dg = g0.x*tl[0]+g0.y*tl[1]+g0.z*tl[2]+g0.w*tl[3]
                 + g1.x*tl[4]+g1.y*tl[5]+g1.z*tl[6]+g1.w*tl[7]
                 + g2.x*tl[8]+g2.y*tl[9]+g2.z*tl[10]+g2.w*tl[11]
                 + g3.x*tl[12]+g3.y*tl[13]+g3.z*tl[14]+g3.w*tl[15];
        float du = u0.x*tl[0]+u0.y*tl[1]+u0.z*tl[2]+u0.w*tl[3]
                 + u1.x*tl[4]+u1.y*tl[5]+u1.z*tl[6]+u1.w*tl[7]
                 + u2.x*tl[8]+u2.y*tl[9]+u2.z*tl[10]+u2.w*tl[11]
                 + u3.x*tl[12]+u3.y*tl[13]+u3.z*tl[14]+u3.w*tl[15];
        float gate = c1r[i] + dg * s;
        float up   = c1r[Id + i] + du * s;
        float v = gate / (1.f + __expf(-gate)) * up;
        actr[i] = f2bf(v);
    }
}

// ---------------- fused down LoRA + routed-weight moe_sum ----------------
__global__ __launch_bounds__(256) void k_dfinal(
    const ushort* __restrict__ act, const float* __restrict__ Ad,
    const float* __restrict__ Bd, const float* __restrict__ scal,
    const int* __restrict__ topk_ids, const int* __restrict__ lidx,
    const float* __restrict__ tw, const float* __restrict__ cache3,
    float* __restrict__ out)
{
    const int t = blockIdx.x;
    const int l = lidx[t];
    const float s = scal[l];
    const int e0 = topk_ids[t * 2], e1 = topk_ids[t * 2 + 1];
    const float w0 = tw[t * 2], w1 = tw[t * 2 + 1];
    __shared__ float tmp[2][Rd];

    const int tid = threadIdx.x, lane = tid & 63, wave = tid >> 6;
    const int r = wave * 4 + (lane >> 4);
    const int hl = lane & 15;
    #pragma unroll
    for (int k = 0; k < 2; ++k) {
        const int e = k ? e1 : e0;
        const float* arow = Ad + (((size_t)l * Ed + e) * Rd + r) * Id;
        const ushort* xr = act + (size_t)(t * 2 + k) * Id;
        float a = 0.f;
        for (int h0 = hl * 4; h0 < Id; h0 += 64) {
            float4 av = *reinterpret_cast<const float4*>(&arow[h0]);
            ushort4 xv = *reinterpret_cast<const ushort4*>(&xr[h0]);
            a += av.x * bf2f(xv.x) + av.y * bf2f(xv.y) + av.z * bf2f(xv.z) + av.w * bf2f(xv.w);
        }
        a += __shfl_xor(a, 1); a += __shfl_xor(a, 2);
        a += __shfl_xor(a, 4); a += __shfl_xor(a, 8);
        if (hl == 0) tmp[k][r] = a;
    }
    __syncthreads();

    float t0[Rd], t1[Rd];
    #pragma unroll
    for (int q = 0; q < Rd; ++q) { t0[q] = tmp[0][q]; t1[q] = tmp[1][q]; }
    const float* B0 = Bd + ((size_t)l * Ed + e0) * Hd * Rd;
    const float* B1 = Bd + ((size_t)l * Ed + e1) * Hd * Rd;
    const float* c30 = cache3 + (size_t)(t * 2) * Hd;
    const float* c31 = cache3 + (size_t)(t * 2 + 1) * Hd;
    float* outr = out + (size_t)t * Hd;
    #pragma unroll
    for (int hh = 0; hh < Hd / 256; ++hh) {
        int h = hh * 256 + tid;
        const float4* b0 = reinterpret_cast<const float4*>(B0 + (size_t)h * Rd);
        const float4* b1 = reinterpret_cast<const float4*>(B1 + (size_t)h * Rd);
        float4 a0 = b0[0], a1 = b0[1], a2 = b0[2], a3 = b0[3];
        float4 c0 = b1[0], c1 = b1[1], c2 = b1[2], c3 = b1[3];
        float d0 = a0.x*t0[0]+a0.y*t0[1]+a0.z*t0[2]+a0.w*t0[3]
                 + a1.x*t0[4]+a1.y*t0[5]+a1.z*t0[6]+a1.w*t0[7]
                 + a2.x*t0[8]+a2.y*t0[9]+a2.z*t0[10]+a2.w*t0[11]
                 + a3.x*t0[12]+a3.y*t0[13]+a3.z*t0[14]+a3.w*t0[15];
        float d1 = c0.x*t1[0]+c0.y*t1[1]+c0.z*t1[2]+c0.w*t1[3]
                 + c1.x*t1[4]+c1.y*t1[5]+c1.z*t1[6]+c1.w*t1[7]
                 + c2.x*t1[8]+c2.y*t1[9]+c2.z*t1[10]+c2.w*t1[11]
                 + c3.x*t1[12]+c3.y*t1[13]+c3.z*t1[14]+c3.w*t1[15];
        outr[h] = w0 * (c30[h] + s * d0) + w1 * (c31[h] + s * d1);
    }
}

extern "C" void kernel_launch(void* const* d_in, const int* in_sizes, int n_in,
                              void* d_out, int out_size, void* d_ws, size_t ws_size,
                              hipStream_t stream) {
    const float* hid  = (const float*)d_in[0];
    const float* tw   = (const float*)d_in[1];
    const float* w13  = (const float*)d_in[2];
    const float* w2   = (const float*)d_in[3];
    const float* ga   = (const float*)d_in[4];
    const float* gb   = (const float*)d_in[5];
    const float* da   = (const float*)d_in[6];
    const float* db   = (const float*)d_in[7];
    const float* sc   = (const float*)d_in[8];
    const int*   tids = (const int*)d_in[9];
    const int*   lidx = (const int*)d_in[10];
    float* out = (float*)d_out;

    char* ws = (char*)d_ws;
    ushort* xb     = (ushort*)(ws);                         // 2 MB
    ushort* w13b   = (ushort*)(ws + (2ull  << 20));         // 32 MB
    ushort* w2b    = (ushort*)(ws + (34ull << 20));         // 16 MB
    float*  cache1 = (float*)(ws + (50ull << 20));          // 16 MB
    ushort* act    = (ushort*)(ws + (66ull << 20));         // 4 MB
    float*  cache3 = (float*)(ws + (70ull << 20));          // 8 MB
    int*    sorted = (int*)(ws + (78ull << 20));            // 8 KB
    int*    offs   = (int*)(ws + (78ull << 20) + TKd * 4);  // 36 B

    constexpr int CVT_BLOCKS = (Td * Hd + Ed * Nd * Hd + Ed * Hd * Id) / 8 / 256;
    k_route<<<1, 1024, 0, stream>>>(tids, sorted, offs);
    k_convert<<<CVT_BLOCKS, 256, 0, stream>>>(hid, w13, w2, xb, w13b, w2b);
    k_gemm4<Nd, 128, 128, true><<<384, 256, 0, stream>>>(xb, w13b, cache1, sorted, offs);
    k_lsilu<<<TKd, 256, 0, stream>>>(hid, ga, gb, sc, tids, lidx, cache1, act);
    k_gemm4<Hd, 128, 64, false><<<384, 256, 0, stream>>>(act, w2b, cache3, sorted, offs);
    k_dfinal<<<Td, 256, 0, stream>>>(act, da, db, sc, tids, lidx, tw, cache3, out);
}

// Round 5
// 114.328 us; speedup vs baseline: 1.3836x; 1.2509x over previous
//
#include <hip/hip_runtime.h>
#include <stdint.h>

#define Td 1024
#define Hd 1024
#define Id 1024
#define Ed 8
#define Kd 2
#define Ld 4
#define Rd 16
#define Nd 2048
#define TKd (Td*Kd)

typedef __bf16 bf16x8 __attribute__((ext_vector_type(8)));
typedef float f32x4 __attribute__((ext_vector_type(4)));

__device__ __forceinline__ ushort f2bf(float f) {
    uint32_t u = __builtin_bit_cast(uint32_t, f);
    return (ushort)((u + 0x7fffu + ((u >> 16) & 1u)) >> 16);
}
__device__ __forceinline__ float bf2f(ushort u) {
    uint32_t x = ((uint32_t)u) << 16;
    return __builtin_bit_cast(float, x);
}

#define GLOAD_LDS16(g, l) __builtin_amdgcn_global_load_lds( \
    (const __attribute__((address_space(1))) uint32_t*)(const void*)(g), \
    (__attribute__((address_space(3))) uint32_t*)(void*)(l), 16, 0, 0)

// ---------------- convert x + w13 + w2 fp32 -> bf16 ----------------
__global__ void k_convert(const float* __restrict__ x, const float* __restrict__ w13,
                          const float* __restrict__ w2, ushort* __restrict__ xb,
                          ushort* __restrict__ w13b, ushort* __restrict__ w2b) {
    constexpr int X8   = Td * Hd / 8;
    constexpr int W138 = Ed * Nd * Hd / 8;
    int i = blockIdx.x * blockDim.x + threadIdx.x;     // 8 floats per thread
    const float* src; ushort* dst; size_t off;
    if (i < X8)              { src = x;   dst = xb;   off = (size_t)i * 8; }
    else if (i < X8 + W138)  { src = w13; dst = w13b; off = (size_t)(i - X8) * 8; }
    else                     { src = w2;  dst = w2b;  off = (size_t)(i - X8 - W138) * 8; }
    float4 a = *reinterpret_cast<const float4*>(src + off);
    float4 b = *reinterpret_cast<const float4*>(src + off + 4);
    uint4 o;
    o.x = (uint)f2bf(a.x) | ((uint)f2bf(a.y) << 16);
    o.y = (uint)f2bf(a.z) | ((uint)f2bf(a.w) << 16);
    o.z = (uint)f2bf(b.x) | ((uint)f2bf(b.y) << 16);
    o.w = (uint)f2bf(b.z) | ((uint)f2bf(b.w) << 16);
    *reinterpret_cast<uint4*>(dst + off) = o;
}

// ---------------- build l-interleaved LoRA-B ext matrices (bf16) ----------------
// gbbe[e][n][l*16+r] = gb[l][e][n][r];  dbbe[e][h][l*16+r] = db[l][e][h][r]
__global__ void k_convb(const float* __restrict__ gb, const float* __restrict__ db,
                        ushort* __restrict__ gbbe, ushort* __restrict__ dbbe) {
    constexpr int GR = Ld * Ed * Nd;     // 65536 rows of 16
    int i = blockIdx.x * blockDim.x + threadIdx.x;
    const float* src; ushort* dst;
    int l, e, n;
    if (i < GR) {
        l = i >> 14; e = (i >> 11) & 7; n = i & 2047;
        src = gb + (size_t)i * 16;
        dst = gbbe + ((size_t)(e * Nd + n)) * 64 + l * 16;
    } else {
        int j = i - GR;                  // Ld*Ed*Id rows
        l = j >> 13; e = (j >> 10) & 7; n = j & 1023;
        src = db + (size_t)j * 16;
        dst = dbbe + ((size_t)(e * Id + n)) * 64 + l * 16;
    }
    float4 a0 = *(const float4*)(src);
    float4 a1 = *(const float4*)(src + 4);
    float4 a2 = *(const float4*)(src + 8);
    float4 a3 = *(const float4*)(src + 12);
    uint4 o;
    o.x = (uint)f2bf(a0.x) | ((uint)f2bf(a0.y) << 16);
    o.y = (uint)f2bf(a0.z) | ((uint)f2bf(a0.w) << 16);
    o.z = (uint)f2bf(a1.x) | ((uint)f2bf(a1.y) << 16);
    o.w = (uint)f2bf(a1.z) | ((uint)f2bf(a1.w) << 16);
    *(uint4*)(dst) = o;
    o.x = (uint)f2bf(a2.x) | ((uint)f2bf(a2.y) << 16);
    o.y = (uint)f2bf(a2.z) | ((uint)f2bf(a2.w) << 16);
    o.z = (uint)f2bf(a3.x) | ((uint)f2bf(a3.y) << 16);
    o.w = (uint)f2bf(a3.z) | ((uint)f2bf(a3.w) << 16);
    *(uint4*)(dst + 8) = o;
}

// ---------------- route sort: bucket pairs by expert ----------------
__global__ void k_route(const int* __restrict__ topk_ids, int* __restrict__ sorted,
                        int* __restrict__ offs) {
    __shared__ int cnt[Ed];
    __shared__ int cur[Ed];
    int tid = threadIdx.x;
    if (tid < Ed) cnt[tid] = 0;
    __syncthreads();
    int e0 = topk_ids[tid];
    int e1 = topk_ids[tid + 1024];
    atomicAdd(&cnt[e0], 1);
    atomicAdd(&cnt[e1], 1);
    __syncthreads();
    if (tid == 0) {
        int s = 0;
        for (int e = 0; e < Ed; ++e) { offs[e] = s; cur[e] = s; s += cnt[e]; }
        offs[Ed] = s;
    }
    __syncthreads();
    int pos = atomicAdd(&cur[e0], 1);
    sorted[pos] = tid;
    pos = atomicAdd(&cur[e1], 1);
    sorted[pos] = tid + 1024;
}

// ---------------- LoRA-A projection: tmpe[p][l*16+r] = s * (A[l,e] @ xrow), zeros elsewhere ----------------
// XBF=false: x = hid fp32, row p>>1.  XBF=true: x = act bf16, row p.
template<bool XBF>
__global__ __launch_bounds__(256) void k_tmp(
    const void* __restrict__ xsrc, const float* __restrict__ Alora,
    const float* __restrict__ scal, const int* __restrict__ topk_ids,
    const int* __restrict__ lidx, ushort* __restrict__ tmpe)
{
    const int p = blockIdx.x;
    const int e = topk_ids[p];
    const int l = lidx[p >> 1];
    const float s = scal[l];
    const int tid = threadIdx.x;
    const int r = tid >> 4, q = tid & 15;
    const float* A = Alora + (((size_t)l * Ed + e) * Rd + r) * 1024;
    float sum = 0.f;
    if (!XBF) {
        const float* x = (const float*)xsrc + (size_t)(p >> 1) * 1024;
        #pragma unroll
        for (int i = 0; i < 16; ++i) {
            int h = q * 4 + 64 * i;
            float4 a = *(const float4*)(A + h);
            float4 v = *(const float4*)(x + h);
            sum += a.x * v.x + a.y * v.y + a.z * v.z + a.w * v.w;
        }
    } else {
        const ushort* x = (const ushort*)xsrc + (size_t)p * 1024;
        #pragma unroll
        for (int i = 0; i < 8; ++i) {
            int h = q * 8 + 128 * i;
            float4 a0 = *(const float4*)(A + h);
            float4 a1 = *(const float4*)(A + h + 4);
            ushort4 v0 = *(const ushort4*)(x + h);
            ushort4 v1 = *(const ushort4*)(x + h + 4);
            sum += a0.x * bf2f(v0.x) + a0.y * bf2f(v0.y) + a0.z * bf2f(v0.z) + a0.w * bf2f(v0.w)
                 + a1.x * bf2f(v1.x) + a1.y * bf2f(v1.y) + a1.z * bf2f(v1.z) + a1.w * bf2f(v1.w);
        }
    }
    sum += __shfl_xor(sum, 1); sum += __shfl_xor(sum, 2);
    sum += __shfl_xor(sum, 4); sum += __shfl_xor(sum, 8);
    __shared__ float tr[Rd];
    if (q == 0) tr[r] = sum;
    __syncthreads();
    if (tid < 32) {
        int j0 = tid * 2;
        uint v = 0;
        if ((j0 >> 4) == l)
            v = (uint)f2bf(s * tr[j0 & 15]) | ((uint)f2bf(s * tr[(j0 + 1) & 15]) << 16);
        ((uint*)(tmpe + (size_t)p * 64))[tid] = v;
    }
}

// ---------------- grouped GEMM + fused LoRA-B ext K-steps ----------------
// C[p,n] = sum_k A[row(p),k]*B[e][n,k] + sum_j Aext[p,j]*Bext[e][n,j]  (j<64)
template<int NC, int BN, bool ROWDIV>
__global__ __launch_bounds__(256) void k_gemm5(
    const ushort* __restrict__ Ab, const ushort* __restrict__ Bb,
    const ushort* __restrict__ Aext, const ushort* __restrict__ Bext,
    float* __restrict__ C, const int* __restrict__ sorted,
    const int* __restrict__ offs)
{
    constexpr int BM = 128;
    constexpr int NTN = NC / BN;            // 16 for both instantiations
    constexpr int MREP = 4;
    constexpr int NREP = BN / 32;
    constexpr int RA = 2;                   // 512 A-chunks / 256 threads
    constexpr int RB = BN * 4 / 256;

    __shared__ ushort As[BM][32];
    __shared__ ushort Bs[BN][32];

    const int tid = threadIdx.x;
    const int lane = tid & 63;
    const int wave = tid >> 6;
    const int wr = wave >> 1, wc = wave & 1;
    const int fr = lane & 15;
    const int fk = (lane >> 4) * 8;

    int off[Ed + 1];
    #pragma unroll
    for (int e = 0; e <= Ed; ++e) off[e] = offs[e];
    int mt[Ed]; int tot = 0;
    #pragma unroll
    for (int e = 0; e < Ed; ++e) {
        mt[e] = (off[e + 1] - off[e] + BM - 1) / BM;
        tot += mt[e] * NTN;
    }

    for (int tau = blockIdx.x; tau < tot; tau += gridDim.x) {
        int t = tau, e = 0;
        while (t >= mt[e] * NTN) { t -= mt[e] * NTN; ++e; }
        const int m0 = off[e] + (t >> 4) * BM;
        const int mend = off[e + 1];
        const int n0 = (t & 15) * BN;

        const ushort* asrc[RA]; const ushort* aesrc[RA];
        #pragma unroll
        for (int r = 0; r < RA; ++r) {
            int c = r * 256 + tid;
            int row = c >> 2, kc = c & 3;
            int aIdx = m0 + row; if (aIdx > mend - 1) aIdx = mend - 1;
            int p = sorted[aIdx];
            int ar = ROWDIV ? (p >> 1) : p;
            asrc[r]  = Ab + (size_t)ar * 1024 + kc * 8;
            aesrc[r] = Aext + (size_t)p * 64 + kc * 8;
        }
        const ushort* bsrc[RB]; const ushort* besrc[RB];
        #pragma unroll
        for (int r = 0; r < RB; ++r) {
            int c = r * 256 + tid;
            int row = c >> 2, kc = c & 3;
            bsrc[r]  = Bb + ((size_t)e * NC + n0 + row) * 1024 + kc * 8;
            besrc[r] = Bext + ((size_t)e * NC + n0 + row) * 64 + kc * 8;
        }

        f32x4 acc[MREP][NREP] = {};

        auto step = [&]() {
            bf16x8 af[MREP], bfv[NREP];
            #pragma unroll
            for (int mi = 0; mi < MREP; ++mi)
                af[mi] = *(const bf16x8*)(&As[wr * 64 + mi * 16 + fr][fk]);
            #pragma unroll
            for (int ni = 0; ni < NREP; ++ni)
                bfv[ni] = *(const bf16x8*)(&Bs[wc * (BN / 2) + ni * 16 + fr][fk]);
            #pragma unroll
            for (int mi = 0; mi < MREP; ++mi)
                #pragma unroll
                for (int ni = 0; ni < NREP; ++ni)
                    acc[mi][ni] = __builtin_amdgcn_mfma_f32_16x16x32_bf16(
                        af[mi], bfv[ni], acc[mi][ni], 0, 0, 0);
        };

        for (int k0 = 0; k0 < 1024; k0 += 32) {
            #pragma unroll
            for (int r = 0; r < RA; ++r)
                GLOAD_LDS16(asrc[r] + k0, (char*)&As[0][0] + (r * 256 + wave * 64) * 16);
            #pragma unroll
            for (int r = 0; r < RB; ++r)
                GLOAD_LDS16(bsrc[r] + k0, (char*)&Bs[0][0] + (r * 256 + wave * 64) * 16);
            __syncthreads();
            step();
            __syncthreads();
        }
        // LoRA-B ext: 2 K-steps over the 64-wide l-interleaved slot space
        #pragma unroll
        for (int es = 0; es < 2; ++es) {
            #pragma unroll
            for (int r = 0; r < RA; ++r)
                GLOAD_LDS16(aesrc[r] + es * 32, (char*)&As[0][0] + (r * 256 + wave * 64) * 16);
            #pragma unroll
            for (int r = 0; r < RB; ++r)
                GLOAD_LDS16(besrc[r] + es * 32, (char*)&Bs[0][0] + (r * 256 + wave * 64) * 16);
            __syncthreads();
            step();
            __syncthreads();
        }

        // epilogue: D layout col=lane&15 (n), row=(lane>>4)*4+j (m)
        const int rb = wr * 64 + (lane >> 4) * 4;
        #pragma unroll
        for (int mi = 0; mi < MREP; ++mi) {
            #pragma unroll
            for (int j = 0; j < 4; ++j) {
                int sidx = m0 + rb + mi * 16 + j;
                if (sidx < mend) {
                    int p = sorted[sidx];
                    float* cr = C + (size_t)p * NC + n0 + wc * (BN / 2) + fr;
                    #pragma unroll
                    for (int ni = 0; ni < NREP; ++ni)
                        cr[ni * 16] = acc[mi][ni][j];
                }
            }
        }
    }
}

// ---------------- silu_and_mul -> bf16 act ----------------
__global__ void k_silu(const float* __restrict__ c1, ushort* __restrict__ act) {
    int i = blockIdx.x * blockDim.x + threadIdx.x;  // one float4 per thread
    int p = i >> 8;
    int c = (i & 255) * 4;
    float4 g = *reinterpret_cast<const float4*>(&c1[(size_t)p * Nd + c]);
    float4 u = *reinterpret_cast<const float4*>(&c1[(size_t)p * Nd + Id + c]);
    float r0 = g.x / (1.f + __expf(-g.x)) * u.x;
    float r1 = g.y / (1.f + __expf(-g.y)) * u.y;
    float r2 = g.z / (1.f + __expf(-g.z)) * u.z;
    float r3 = g.w / (1.f + __expf(-g.w)) * u.w;
    uint2 o;
    o.x = (uint)f2bf(r0) | ((uint)f2bf(r1) << 16);
    o.y = (uint)f2bf(r2) | ((uint)f2bf(r3) << 16);
    *reinterpret_cast<uint2*>(&act[(size_t)p * Id + c]) = o;
}

// ---------------- finalize: out[t] = w0*c3[2t] + w1*c3[2t+1] ----------------
__global__ void k_final(const float* __restrict__ c3, const float* __restrict__ tw,
                        float* __restrict__ out) {
    int i = blockIdx.x * blockDim.x + threadIdx.x;
    int t = i >> 8;
    int c = (i & 255) * 4;
    float w0 = tw[t * 2], w1 = tw[t * 2 + 1];
    float4 a = *reinterpret_cast<const float4*>(&c3[((size_t)t * 2) * Hd + c]);
    float4 b = *reinterpret_cast<const float4*>(&c3[((size_t)t * 2 + 1) * Hd + c]);
    float4 o;
    o.x = w0 * a.x + w1 * b.x;
    o.y = w0 * a.y + w1 * b.y;
    o.z = w0 * a.z + w1 * b.z;
    o.w = w0 * a.w + w1 * b.w;
    *reinterpret_cast<float4*>(&out[(size_t)t * Hd + c]) = o;
}

extern "C" void kernel_launch(void* const* d_in, const int* in_sizes, int n_in,
                              void* d_out, int out_size, void* d_ws, size_t ws_size,
                              hipStream_t stream) {
    const float* hid  = (const float*)d_in[0];
    const float* tw   = (const float*)d_in[1];
    const float* w13  = (const float*)d_in[2];
    const float* w2   = (const float*)d_in[3];
    const float* ga   = (const float*)d_in[4];
    const float* gb   = (const float*)d_in[5];
    const float* da   = (const float*)d_in[6];
    const float* db   = (const float*)d_in[7];
    const float* sc   = (const float*)d_in[8];
    const int*   tids = (const int*)d_in[9];
    const int*   lidx = (const int*)d_in[10];
    float* out = (float*)d_out;

    char* ws = (char*)d_ws;
    ushort* xb     = (ushort*)(ws);                          // 2 MB
    ushort* w13b   = (ushort*)(ws + (2ull  << 20));          // 32 MB
    ushort* w2b    = (ushort*)(ws + (34ull << 20));          // 16 MB
    ushort* gbbe   = (ushort*)(ws + (50ull << 20));          // 2 MB
    ushort* dbbe   = (ushort*)(ws + (52ull << 20));          // 1 MB
    ushort* tmp1e  = (ushort*)(ws + (53ull << 20));          // 256 KB
    ushort* tmpde  = (ushort*)(ws + (53ull << 20) + (256u << 10)); // 256 KB
    float*  cache1 = (float*)(ws + (54ull << 20));           // 16 MB
    float*  cache3 = (float*)(ws + (54ull << 20));           // overlays cache1 (dead after silu)
    ushort* act    = (ushort*)(ws + (70ull << 20));          // 4 MB
    int*    sorted = (int*)(ws + (74ull << 20));             // 8 KB
    int*    offs   = (int*)(ws + (74ull << 20) + TKd * 4);   // 36 B

    constexpr int CVT_BLOCKS = (Td * Hd + Ed * Nd * Hd + Ed * Hd * Id) / 8 / 256;
    constexpr int CVB_BLOCKS = (Ld * Ed * Nd + Ld * Ed * Id) / 256;

    k_route<<<1, 1024, 0, stream>>>(tids, sorted, offs);
    k_tmp<false><<<TKd, 256, 0, stream>>>(hid, ga, sc, tids, lidx, tmp1e);
    k_convert<<<CVT_BLOCKS, 256, 0, stream>>>(hid, w13, w2, xb, w13b, w2b);
    k_convb<<<CVB_BLOCKS, 256, 0, stream>>>(gb, db, gbbe, dbbe);
    k_gemm5<Nd, 128, true><<<512, 256, 0, stream>>>(xb, w13b, tmp1e, gbbe, cache1, sorted, offs);
    k_silu<<<(TKd * Id / 4) / 256, 256, 0, stream>>>(cache1, act);
    k_tmp<true><<<TKd, 256, 0, stream>>>(act, da, sc, tids, lidx, tmpde);
    k_gemm5<Hd, 64, false><<<512, 256, 0, stream>>>(act, w2b, tmpde, dbbe, cache3, sorted, offs);
    k_final<<<(Td * Hd / 4) / 256, 256, 0, stream>>>(cache3, tw, out);
}

// Round 6
// 107.179 us; speedup vs baseline: 1.4759x; 1.0667x over previous
//
#include <hip/hip_runtime.h>
#include <stdint.h>

#define Td 1024
#define Hd 1024
#define Id 1024
#define Ed 8
#define Kd 2
#define Ld 4
#define Rd 16
#define Nd 2048
#define TKd (Td*Kd)

typedef __bf16 bf16x8 __attribute__((ext_vector_type(8)));
typedef float f32x4 __attribute__((ext_vector_type(4)));

__device__ __forceinline__ ushort f2bf(float f) {
    uint32_t u = __builtin_bit_cast(uint32_t, f);
    return (ushort)((u + 0x7fffu + ((u >> 16) & 1u)) >> 16);
}
__device__ __forceinline__ float bf2f(ushort u) {
    uint32_t x = ((uint32_t)u) << 16;
    return __builtin_bit_cast(float, x);
}

#define GLOAD_LDS16(g, l) __builtin_amdgcn_global_load_lds( \
    (const __attribute__((address_space(1))) uint32_t*)(const void*)(g), \
    (__attribute__((address_space(3))) uint32_t*)(void*)(l), 16, 0, 0)

// block-role partition of k_prep
#define WB 12288   // weight convert blocks (w13+w2, 8 floats/thread)
#define XB 512     // x convert blocks
#define CB 384     // LoRA-B interleave blocks (rows of 16)
#define TB 2048    // gate_up LoRA-A projection blocks (one per pair)
#define ZB 1024    // out zeroing blocks (one float4/thread)
#define PREP_BLOCKS (WB + XB + CB + TB + ZB + 1)

__global__ __launch_bounds__(256) void k_prep(
    const float* __restrict__ hid, const float* __restrict__ w13,
    const float* __restrict__ w2, const float* __restrict__ gb,
    const float* __restrict__ db, const float* __restrict__ ga,
    const float* __restrict__ sc, const int* __restrict__ tids,
    const int* __restrict__ lidx,
    ushort* __restrict__ xb, ushort* __restrict__ w13b, ushort* __restrict__ w2b,
    ushort* __restrict__ gbbe, ushort* __restrict__ dbbe, ushort* __restrict__ tmp1e,
    float* __restrict__ out, int* __restrict__ sorted, int* __restrict__ offs)
{
    __shared__ float tr[Rd];
    __shared__ int cnt[Ed];
    __shared__ int cur[Ed];
    const int b = blockIdx.x, tid = threadIdx.x;

    if (b < WB) {
        // ---- weights fp32 -> bf16 ----
        constexpr int W138 = Ed * Nd * Hd / 8;
        int i = b * 256 + tid;
        const float* src; ushort* dst; size_t off;
        if (i < W138) { src = w13; dst = w13b; off = (size_t)i * 8; }
        else          { src = w2;  dst = w2b;  off = (size_t)(i - W138) * 8; }
        float4 a = *(const float4*)(src + off);
        float4 c = *(const float4*)(src + off + 4);
        uint4 o;
        o.x = (uint)f2bf(a.x) | ((uint)f2bf(a.y) << 16);
        o.y = (uint)f2bf(a.z) | ((uint)f2bf(a.w) << 16);
        o.z = (uint)f2bf(c.x) | ((uint)f2bf(c.y) << 16);
        o.w = (uint)f2bf(c.z) | ((uint)f2bf(c.w) << 16);
        *(uint4*)(dst + off) = o;
    } else if (b < WB + XB) {
        // ---- x fp32 -> bf16 ----
        int i = (b - WB) * 256 + tid;
        size_t off = (size_t)i * 8;
        float4 a = *(const float4*)(hid + off);
        float4 c = *(const float4*)(hid + off + 4);
        uint4 o;
        o.x = (uint)f2bf(a.x) | ((uint)f2bf(a.y) << 16);
        o.y = (uint)f2bf(a.z) | ((uint)f2bf(a.w) << 16);
        o.z = (uint)f2bf(c.x) | ((uint)f2bf(c.y) << 16);
        o.w = (uint)f2bf(c.z) | ((uint)f2bf(c.w) << 16);
        *(uint4*)(xb + off) = o;
    } else if (b < WB + XB + CB) {
        // ---- LoRA-B l-interleave: gbbe[e][n][l*16+r] = gb[l][e][n][r] (same for db) ----
        constexpr int GR = Ld * Ed * Nd;
        int i = (b - WB - XB) * 256 + tid;
        const float* src; ushort* dst;
        if (i < GR) {
            int l = i >> 14, e = (i >> 11) & 7, n = i & 2047;
            src = gb + (size_t)i * 16;
            dst = gbbe + ((size_t)(e * Nd + n)) * 64 + l * 16;
        } else {
            int j = i - GR;
            int l = j >> 13, e = (j >> 10) & 7, n = j & 1023;
            src = db + (size_t)j * 16;
            dst = dbbe + ((size_t)(e * Id + n)) * 64 + l * 16;
        }
        float4 a0 = *(const float4*)(src);
        float4 a1 = *(const float4*)(src + 4);
        float4 a2 = *(const float4*)(src + 8);
        float4 a3 = *(const float4*)(src + 12);
        uint4 o;
        o.x = (uint)f2bf(a0.x) | ((uint)f2bf(a0.y) << 16);
        o.y = (uint)f2bf(a0.z) | ((uint)f2bf(a0.w) << 16);
        o.z = (uint)f2bf(a1.x) | ((uint)f2bf(a1.y) << 16);
        o.w = (uint)f2bf(a1.z) | ((uint)f2bf(a1.w) << 16);
        *(uint4*)(dst) = o;
        o.x = (uint)f2bf(a2.x) | ((uint)f2bf(a2.y) << 16);
        o.y = (uint)f2bf(a2.z) | ((uint)f2bf(a2.w) << 16);
        o.z = (uint)f2bf(a3.x) | ((uint)f2bf(a3.y) << 16);
        o.w = (uint)f2bf(a3.z) | ((uint)f2bf(a3.w) << 16);
        *(uint4*)(dst + 8) = o;
    } else if (b < WB + XB + CB + TB) {
        // ---- gate_up LoRA-A projection: tmp1e[p][l*16+r] = s*(Ag[l,e]@x[t]) ----
        const int p = b - WB - XB - CB;
        const int e = tids[p];
        const int l = lidx[p >> 1];
        const float s = sc[l];
        const int r = tid >> 4, q = tid & 15;
        const float* A = ga + (((size_t)l * Ed + e) * Rd + r) * 1024;
        const float* x = hid + (size_t)(p >> 1) * 1024;
        float sum = 0.f;
        #pragma unroll
        for (int i = 0; i < 16; ++i) {
            int h = q * 4 + 64 * i;
            float4 a = *(const float4*)(A + h);
            float4 v = *(const float4*)(x + h);
            sum += a.x * v.x + a.y * v.y + a.z * v.z + a.w * v.w;
        }
        sum += __shfl_xor(sum, 1); sum += __shfl_xor(sum, 2);
        sum += __shfl_xor(sum, 4); sum += __shfl_xor(sum, 8);
        if (q == 0) tr[r] = sum;
        __syncthreads();
        if (tid < 32) {
            int j0 = tid * 2;
            uint v = 0;
            if ((j0 >> 4) == l)
                v = (uint)f2bf(s * tr[j0 & 15]) | ((uint)f2bf(s * tr[(j0 + 1) & 15]) << 16);
            ((uint*)(tmp1e + (size_t)p * 64))[tid] = v;
        }
    } else if (b < WB + XB + CB + TB + ZB) {
        // ---- zero out (atomic accumulation target) ----
        int i = (b - WB - XB - CB - TB) * 256 + tid;
        ((float4*)out)[i] = make_float4(0.f, 0.f, 0.f, 0.f);
    } else {
        // ---- route sort (single block, 8 pairs/thread) ----
        if (tid < Ed) cnt[tid] = 0;
        __syncthreads();
        int el[8];
        #pragma unroll
        for (int i = 0; i < 8; ++i) {
            el[i] = tids[tid + i * 256];
            atomicAdd(&cnt[el[i]], 1);
        }
        __syncthreads();
        if (tid == 0) {
            int s = 0;
            for (int e = 0; e < Ed; ++e) { offs[e] = s; cur[e] = s; s += cnt[e]; }
            offs[Ed] = s;
        }
        __syncthreads();
        #pragma unroll
        for (int i = 0; i < 8; ++i) {
            int pos = atomicAdd(&cur[el[i]], 1);
            sorted[pos] = tid + i * 256;
        }
    }
}

// ---------------- down LoRA-A projection (act bf16 input) ----------------
__global__ __launch_bounds__(256) void k_tmp_dn(
    const ushort* __restrict__ act, const float* __restrict__ da,
    const float* __restrict__ sc, const int* __restrict__ tids,
    const int* __restrict__ lidx, ushort* __restrict__ tmpde)
{
    const int p = blockIdx.x;
    const int e = tids[p];
    const int l = lidx[p >> 1];
    const float s = sc[l];
    const int tid = threadIdx.x;
    const int r = tid >> 4, q = tid & 15;
    const float* A = da + (((size_t)l * Ed + e) * Rd + r) * 1024;
    const ushort* x = act + (size_t)p * 1024;
    float sum = 0.f;
    #pragma unroll
    for (int i = 0; i < 8; ++i) {
        int h = q * 8 + 128 * i;
        float4 a0 = *(const float4*)(A + h);
        float4 a1 = *(const float4*)(A + h + 4);
        ushort4 v0 = *(const ushort4*)(x + h);
        ushort4 v1 = *(const ushort4*)(x + h + 4);
        sum += a0.x * bf2f(v0.x) + a0.y * bf2f(v0.y) + a0.z * bf2f(v0.z) + a0.w * bf2f(v0.w)
             + a1.x * bf2f(v1.x) + a1.y * bf2f(v1.y) + a1.z * bf2f(v1.z) + a1.w * bf2f(v1.w);
    }
    sum += __shfl_xor(sum, 1); sum += __shfl_xor(sum, 2);
    sum += __shfl_xor(sum, 4); sum += __shfl_xor(sum, 8);
    __shared__ float tr[Rd];
    if (q == 0) tr[r] = sum;
    __syncthreads();
    if (tid < 32) {
        int j0 = tid * 2;
        uint v = 0;
        if ((j0 >> 4) == l)
            v = (uint)f2bf(s * tr[j0 & 15]) | ((uint)f2bf(s * tr[(j0 + 1) & 15]) << 16);
        ((uint*)(tmpde + (size_t)p * 64))[tid] = v;
    }
}

// ---------------- gate_up GEMM + LoRA-B ext + fused silu -> act bf16 ----------------
// B-tile rows 0-63 = gate cols n0.., rows 64-127 = up cols 1024+n0..
__global__ __launch_bounds__(256) void k_gemm_gu(
    const ushort* __restrict__ xb, const ushort* __restrict__ w13b,
    const ushort* __restrict__ tmp1e, const ushort* __restrict__ gbbe,
    ushort* __restrict__ act, const int* __restrict__ sorted,
    const int* __restrict__ offs)
{
    __shared__ ushort As[128][32];
    __shared__ ushort Bs[128][32];
    const int tid = threadIdx.x, lane = tid & 63, wave = tid >> 6;
    const int wr = wave >> 1, wc = wave & 1;
    const int fr = lane & 15, fk = (lane >> 4) * 8;

    int off[Ed + 1];
    #pragma unroll
    for (int e = 0; e <= Ed; ++e) off[e] = offs[e];
    int mt[Ed]; int tot = 0;
    #pragma unroll
    for (int e = 0; e < Ed; ++e) {
        mt[e] = (off[e + 1] - off[e] + 127) / 128;
        tot += mt[e] * 16;
    }

    for (int tau = blockIdx.x; tau < tot; tau += gridDim.x) {
        int t = tau, e = 0;
        while (t >= mt[e] * 16) { t -= mt[e] * 16; ++e; }
        const int m0 = off[e] + (t >> 4) * 128;
        const int mend = off[e + 1];
        const int n0 = (t & 15) * 64;

        const ushort *asrc[2], *aesrc[2], *bsrc[2], *besrc[2];
        #pragma unroll
        for (int r = 0; r < 2; ++r) {
            int c = r * 256 + tid;
            int row = c >> 2, kc = c & 3;
            int aIdx = m0 + row; if (aIdx > mend - 1) aIdx = mend - 1;
            int p = sorted[aIdx];
            asrc[r]  = xb + (size_t)(p >> 1) * 1024 + kc * 8;
            aesrc[r] = tmp1e + (size_t)p * 64 + kc * 8;
            int grow = (row < 64) ? (n0 + row) : (1024 + n0 + row - 64);
            bsrc[r]  = w13b + ((size_t)e * Nd + grow) * 1024 + kc * 8;
            besrc[r] = gbbe + ((size_t)e * Nd + grow) * 64 + kc * 8;
        }

        f32x4 ag[4][2] = {}, au[4][2] = {};
        auto step = [&]() {
            bf16x8 af[4], bg[2], bu[2];
            #pragma unroll
            for (int mi = 0; mi < 4; ++mi)
                af[mi] = *(const bf16x8*)(&As[wr * 64 + mi * 16 + fr][fk]);
            #pragma unroll
            for (int ni = 0; ni < 2; ++ni) {
                bg[ni] = *(const bf16x8*)(&Bs[wc * 32 + ni * 16 + fr][fk]);
                bu[ni] = *(const bf16x8*)(&Bs[64 + wc * 32 + ni * 16 + fr][fk]);
            }
            #pragma unroll
            for (int mi = 0; mi < 4; ++mi)
                #pragma unroll
                for (int ni = 0; ni < 2; ++ni) {
                    ag[mi][ni] = __builtin_amdgcn_mfma_f32_16x16x32_bf16(af[mi], bg[ni], ag[mi][ni], 0, 0, 0);
                    au[mi][ni] = __builtin_amdgcn_mfma_f32_16x16x32_bf16(af[mi], bu[ni], au[mi][ni], 0, 0, 0);
                }
        };

        for (int k0 = 0; k0 < 1024; k0 += 32) {
            #pragma unroll
            for (int r = 0; r < 2; ++r) {
                GLOAD_LDS16(asrc[r] + k0, (char*)&As[0][0] + (r * 256 + wave * 64) * 16);
                GLOAD_LDS16(bsrc[r] + k0, (char*)&Bs[0][0] + (r * 256 + wave * 64) * 16);
            }
            __syncthreads();
            step();
            __syncthreads();
        }
        #pragma unroll
        for (int es = 0; es < 2; ++es) {
            #pragma unroll
            for (int r = 0; r < 2; ++r) {
                GLOAD_LDS16(aesrc[r] + es * 32, (char*)&As[0][0] + (r * 256 + wave * 64) * 16);
                GLOAD_LDS16(besrc[r] + es * 32, (char*)&Bs[0][0] + (r * 256 + wave * 64) * 16);
            }
            __syncthreads();
            step();
            __syncthreads();
        }

        const int rb = wr * 64 + (lane >> 4) * 4;
        #pragma unroll
        for (int mi = 0; mi < 4; ++mi) {
            #pragma unroll
            for (int j = 0; j < 4; ++j) {
                int sidx = m0 + rb + mi * 16 + j;
                if (sidx < mend) {
                    int p = sorted[sidx];
                    ushort* ar = act + (size_t)p * 1024 + n0 + wc * 32;
                    #pragma unroll
                    for (int ni = 0; ni < 2; ++ni) {
                        float g = ag[mi][ni][j], u = au[mi][ni][j];
                        float v = g / (1.f + __expf(-g)) * u;
                        ar[ni * 16 + fr] = f2bf(v);
                    }
                }
            }
        }
    }
}

// ---------------- down GEMM + LoRA-B ext + fused weighted moe_sum (atomic) ----------------
__global__ __launch_bounds__(256) void k_gemm_dn(
    const ushort* __restrict__ act, const ushort* __restrict__ w2b,
    const ushort* __restrict__ tmpde, const ushort* __restrict__ dbbe,
    const float* __restrict__ tw, float* __restrict__ out,
    const int* __restrict__ sorted, const int* __restrict__ offs)
{
    __shared__ ushort As[128][32];
    __shared__ ushort Bs[64][32];
    const int tid = threadIdx.x, lane = tid & 63, wave = tid >> 6;
    const int wr = wave >> 1, wc = wave & 1;
    const int fr = lane & 15, fk = (lane >> 4) * 8;

    int off[Ed + 1];
    #pragma unroll
    for (int e = 0; e <= Ed; ++e) off[e] = offs[e];
    int mt[Ed]; int tot = 0;
    #pragma unroll
    for (int e = 0; e < Ed; ++e) {
        mt[e] = (off[e + 1] - off[e] + 127) / 128;
        tot += mt[e] * 16;
    }

    for (int tau = blockIdx.x; tau < tot; tau += gridDim.x) {
        int t = tau, e = 0;
        while (t >= mt[e] * 16) { t -= mt[e] * 16; ++e; }
        const int m0 = off[e] + (t >> 4) * 128;
        const int mend = off[e + 1];
        const int n0 = (t & 15) * 64;

        const ushort *asrc[2], *aesrc[2];
        #pragma unroll
        for (int r = 0; r < 2; ++r) {
            int c = r * 256 + tid;
            int row = c >> 2, kc = c & 3;
            int aIdx = m0 + row; if (aIdx > mend - 1) aIdx = mend - 1;
            int p = sorted[aIdx];
            asrc[r]  = act + (size_t)p * 1024 + kc * 8;
            aesrc[r] = tmpde + (size_t)p * 64 + kc * 8;
        }
        const ushort *bsrc, *besrc;
        {
            int row = tid >> 2, kc = tid & 3;
            bsrc  = w2b + ((size_t)e * Hd + n0 + row) * 1024 + kc * 8;
            besrc = dbbe + ((size_t)e * Hd + n0 + row) * 64 + kc * 8;
        }

        f32x4 acc[4][2] = {};
        auto step = [&]() {
            bf16x8 af[4], bv[2];
            #pragma unroll
            for (int mi = 0; mi < 4; ++mi)
                af[mi] = *(const bf16x8*)(&As[wr * 64 + mi * 16 + fr][fk]);
            #pragma unroll
            for (int ni = 0; ni < 2; ++ni)
                bv[ni] = *(const bf16x8*)(&Bs[wc * 32 + ni * 16 + fr][fk]);
            #pragma unroll
            for (int mi = 0; mi < 4; ++mi)
                #pragma unroll
                for (int ni = 0; ni < 2; ++ni)
                    acc[mi][ni] = __builtin_amdgcn_mfma_f32_16x16x32_bf16(af[mi], bv[ni], acc[mi][ni], 0, 0, 0);
        };

        for (int k0 = 0; k0 < 1024; k0 += 32) {
            #pragma unroll
            for (int r = 0; r < 2; ++r)
                GLOAD_LDS16(asrc[r] + k0, (char*)&As[0][0] + (r * 256 + wave * 64) * 16);
            GLOAD_LDS16(bsrc + k0, (char*)&Bs[0][0] + (wave * 64) * 16);
            __syncthreads();
            step();
            __syncthreads();
        }
        #pragma unroll
        for (int es = 0; es < 2; ++es) {
            #pragma unroll
            for (int r = 0; r < 2; ++r)
                GLOAD_LDS16(aesrc[r] + es * 32, (char*)&As[0][0] + (r * 256 + wave * 64) * 16);
            GLOAD_LDS16(besrc + es * 32, (char*)&Bs[0][0] + (wave * 64) * 16);
            __syncthreads();
            step();
            __syncthreads();
        }

        const int rb = wr * 64 + (lane >> 4) * 4;
        #pragma unroll
        for (int mi = 0; mi < 4; ++mi) {
            #pragma unroll
            for (int j = 0; j < 4; ++j) {
                int sidx = m0 + rb + mi * 16 + j;
                if (sidx < mend) {
                    int p = sorted[sidx];
                    float w = tw[p];
                    float* orow = out + (size_t)(p >> 1) * 1024 + n0 + wc * 32;
                    #pragma unroll
                    for (int ni = 0; ni < 2; ++ni)
                        atomicAdd(&orow[ni * 16 + fr], w * acc[mi][ni][j]);
                }
            }
        }
    }
}

extern "C" void kernel_launch(void* const* d_in, const int* in_sizes, int n_in,
                              void* d_out, int out_size, void* d_ws, size_t ws_size,
                              hipStream_t stream) {
    const float* hid  = (const float*)d_in[0];
    const float* tw   = (const float*)d_in[1];
    const float* w13  = (const float*)d_in[2];
    const float* w2   = (const float*)d_in[3];
    const float* ga   = (const float*)d_in[4];
    const float* gb   = (const float*)d_in[5];
    const float* da   = (const float*)d_in[6];
    const float* db   = (const float*)d_in[7];
    const float* sc   = (const float*)d_in[8];
    const int*   tids = (const int*)d_in[9];
    const int*   lidx = (const int*)d_in[10];
    float* out = (float*)d_out;

    char* ws = (char*)d_ws;
    ushort* xb     = (ushort*)(ws);                          // 2 MB
    ushort* w13b   = (ushort*)(ws + (2ull  << 20));          // 32 MB
    ushort* w2b    = (ushort*)(ws + (34ull << 20));          // 16 MB
    ushort* gbbe   = (ushort*)(ws + (50ull << 20));          // 2 MB
    ushort* dbbe   = (ushort*)(ws + (52ull << 20));          // 1 MB
    ushort* tmp1e  = (ushort*)(ws + (53ull << 20));          // 256 KB
    ushort* tmpde  = (ushort*)(ws + (53ull << 20) + (256u << 10)); // 256 KB
    ushort* act    = (ushort*)(ws + (54ull << 20));          // 4 MB
    int*    sorted = (int*)(ws + (58ull << 20));             // 8 KB
    int*    offs   = (int*)(ws + (58ull << 20) + TKd * 4);   // 36 B

    k_prep<<<PREP_BLOCKS, 256, 0, stream>>>(hid, w13, w2, gb, db, ga, sc, tids, lidx,
                                            xb, w13b, w2b, gbbe, dbbe, tmp1e,
                                            out, sorted, offs);
    k_gemm_gu<<<512, 256, 0, stream>>>(xb, w13b, tmp1e, gbbe, act, sorted, offs);
    k_tmp_dn<<<TKd, 256, 0, stream>>>(act, da, sc, tids, lidx, tmpde);
    k_gemm_dn<<<512, 256, 0, stream>>>(act, w2b, tmpde, dbbe, tw, out, sorted, offs);
}

// Round 7
// 100.763 us; speedup vs baseline: 1.5698x; 1.0637x over previous
//
#include <hip/hip_runtime.h>
#include <stdint.h>

#define Td 1024
#define Hd 1024
#define Id 1024
#define Ed 8
#define Kd 2
#define Ld 4
#define Rd 16
#define Nd 2048
#define TKd (Td*Kd)

typedef __bf16 bf16x8 __attribute__((ext_vector_type(8)));
typedef float f32x4 __attribute__((ext_vector_type(4)));

__device__ __forceinline__ ushort f2bf(float f) {
    uint32_t u = __builtin_bit_cast(uint32_t, f);
    return (ushort)((u + 0x7fffu + ((u >> 16) & 1u)) >> 16);
}
__device__ __forceinline__ float bf2f(ushort u) {
    uint32_t x = ((uint32_t)u) << 16;
    return __builtin_bit_cast(float, x);
}
__device__ __forceinline__ bf16x8 pack8(float4 a, float4 b) {
    bf16x8 r;
    r[0] = (__bf16)a.x; r[1] = (__bf16)a.y; r[2] = (__bf16)a.z; r[3] = (__bf16)a.w;
    r[4] = (__bf16)b.x; r[5] = (__bf16)b.y; r[6] = (__bf16)b.z; r[7] = (__bf16)b.w;
    return r;
}

#define GLOAD_LDS16(g, l) __builtin_amdgcn_global_load_lds( \
    (const __attribute__((address_space(1))) uint32_t*)(const void*)(g), \
    (__attribute__((address_space(3))) uint32_t*)(void*)(l), 16, 0, 0)

// block-role partition of k_prep (weights are NOT converted anymore)
#define XB 512     // x convert blocks
#define CB 384     // LoRA-B interleave blocks (rows of 16)
#define TB 2048    // gate_up LoRA-A projection blocks (one per pair)
#define ZB 1024    // out zeroing blocks (one float4/thread)
#define PREP_BLOCKS (XB + CB + TB + ZB + 1)

__global__ __launch_bounds__(256) void k_prep(
    const float* __restrict__ hid, const float* __restrict__ gb,
    const float* __restrict__ db, const float* __restrict__ ga,
    const float* __restrict__ sc, const int* __restrict__ tids,
    const int* __restrict__ lidx,
    ushort* __restrict__ xb, ushort* __restrict__ gbbe, ushort* __restrict__ dbbe,
    ushort* __restrict__ tmp1e, float* __restrict__ out,
    int* __restrict__ sorted, int* __restrict__ offs)
{
    __shared__ float tr[Rd];
    __shared__ int cnt[Ed];
    __shared__ int cur[Ed];
    const int b = blockIdx.x, tid = threadIdx.x;

    if (b < XB) {
        // ---- x fp32 -> bf16 ----
        int i = b * 256 + tid;
        size_t off = (size_t)i * 8;
        float4 a = *(const float4*)(hid + off);
        float4 c = *(const float4*)(hid + off + 4);
        uint4 o;
        o.x = (uint)f2bf(a.x) | ((uint)f2bf(a.y) << 16);
        o.y = (uint)f2bf(a.z) | ((uint)f2bf(a.w) << 16);
        o.z = (uint)f2bf(c.x) | ((uint)f2bf(c.y) << 16);
        o.w = (uint)f2bf(c.z) | ((uint)f2bf(c.w) << 16);
        *(uint4*)(xb + off) = o;
    } else if (b < XB + CB) {
        // ---- LoRA-B l-interleave: gbbe[e][n][l*16+r] = gb[l][e][n][r] (same for db) ----
        constexpr int GR = Ld * Ed * Nd;
        int i = (b - XB) * 256 + tid;
        const float* src; ushort* dst;
        if (i < GR) {
            int l = i >> 14, e = (i >> 11) & 7, n = i & 2047;
            src = gb + (size_t)i * 16;
            dst = gbbe + ((size_t)(e * Nd + n)) * 64 + l * 16;
        } else {
            int j = i - GR;
            int l = j >> 13, e = (j >> 10) & 7, n = j & 1023;
            src = db + (size_t)j * 16;
            dst = dbbe + ((size_t)(e * Id + n)) * 64 + l * 16;
        }
        float4 a0 = *(const float4*)(src);
        float4 a1 = *(const float4*)(src + 4);
        float4 a2 = *(const float4*)(src + 8);
        float4 a3 = *(const float4*)(src + 12);
        uint4 o;
        o.x = (uint)f2bf(a0.x) | ((uint)f2bf(a0.y) << 16);
        o.y = (uint)f2bf(a0.z) | ((uint)f2bf(a0.w) << 16);
        o.z = (uint)f2bf(a1.x) | ((uint)f2bf(a1.y) << 16);
        o.w = (uint)f2bf(a1.z) | ((uint)f2bf(a1.w) << 16);
        *(uint4*)(dst) = o;
        o.x = (uint)f2bf(a2.x) | ((uint)f2bf(a2.y) << 16);
        o.y = (uint)f2bf(a2.z) | ((uint)f2bf(a2.w) << 16);
        o.z = (uint)f2bf(a3.x) | ((uint)f2bf(a3.y) << 16);
        o.w = (uint)f2bf(a3.z) | ((uint)f2bf(a3.w) << 16);
        *(uint4*)(dst + 8) = o;
    } else if (b < XB + CB + TB) {
        // ---- gate_up LoRA-A projection: tmp1e[p][l*16+r] = s*(Ag[l,e]@x[t]) ----
        const int p = b - XB - CB;
        const int e = tids[p];
        const int l = lidx[p >> 1];
        const float s = sc[l];
        const int r = tid >> 4, q = tid & 15;
        const float* A = ga + (((size_t)l * Ed + e) * Rd + r) * 1024;
        const float* x = hid + (size_t)(p >> 1) * 1024;
        float sum = 0.f;
        #pragma unroll
        for (int i = 0; i < 16; ++i) {
            int h = q * 4 + 64 * i;
            float4 a = *(const float4*)(A + h);
            float4 v = *(const float4*)(x + h);
            sum += a.x * v.x + a.y * v.y + a.z * v.z + a.w * v.w;
        }
        sum += __shfl_xor(sum, 1); sum += __shfl_xor(sum, 2);
        sum += __shfl_xor(sum, 4); sum += __shfl_xor(sum, 8);
        if (q == 0) tr[r] = sum;
        __syncthreads();
        if (tid < 32) {
            int j0 = tid * 2;
            uint v = 0;
            if ((j0 >> 4) == l)
                v = (uint)f2bf(s * tr[j0 & 15]) | ((uint)f2bf(s * tr[(j0 + 1) & 15]) << 16);
            ((uint*)(tmp1e + (size_t)p * 64))[tid] = v;
        }
    } else if (b < XB + CB + TB + ZB) {
        // ---- zero out (atomic accumulation target) ----
        int i = (b - XB - CB - TB) * 256 + tid;
        ((float4*)out)[i] = make_float4(0.f, 0.f, 0.f, 0.f);
    } else {
        // ---- route sort (single block, 8 pairs/thread) ----
        if (tid < Ed) cnt[tid] = 0;
        __syncthreads();
        int el[8];
        #pragma unroll
        for (int i = 0; i < 8; ++i) {
            el[i] = tids[tid + i * 256];
            atomicAdd(&cnt[el[i]], 1);
        }
        __syncthreads();
        if (tid == 0) {
            int s = 0;
            for (int e = 0; e < Ed; ++e) { offs[e] = s; cur[e] = s; s += cnt[e]; }
            offs[Ed] = s;
        }
        __syncthreads();
        #pragma unroll
        for (int i = 0; i < 8; ++i) {
            int pos = atomicAdd(&cur[el[i]], 1);
            sorted[pos] = tid + i * 256;
        }
    }
}

// ---------------- down LoRA-A projection (act bf16 input) ----------------
__global__ __launch_bounds__(256) void k_tmp_dn(
    const ushort* __restrict__ act, const float* __restrict__ da,
    const float* __restrict__ sc, const int* __restrict__ tids,
    const int* __restrict__ lidx, ushort* __restrict__ tmpde)
{
    const int p = blockIdx.x;
    const int e = tids[p];
    const int l = lidx[p >> 1];
    const float s = sc[l];
    const int tid = threadIdx.x;
    const int r = tid >> 4, q = tid & 15;
    const float* A = da + (((size_t)l * Ed + e) * Rd + r) * 1024;
    const ushort* x = act + (size_t)p * 1024;
    float sum = 0.f;
    #pragma unroll
    for (int i = 0; i < 8; ++i) {
        int h = q * 8 + 128 * i;
        float4 a0 = *(const float4*)(A + h);
        float4 a1 = *(const float4*)(A + h + 4);
        ushort4 v0 = *(const ushort4*)(x + h);
        ushort4 v1 = *(const ushort4*)(x + h + 4);
        sum += a0.x * bf2f(v0.x) + a0.y * bf2f(v0.y) + a0.z * bf2f(v0.z) + a0.w * bf2f(v0.w)
             + a1.x * bf2f(v1.x) + a1.y * bf2f(v1.y) + a1.z * bf2f(v1.z) + a1.w * bf2f(v1.w);
    }
    sum += __shfl_xor(sum, 1); sum += __shfl_xor(sum, 2);
    sum += __shfl_xor(sum, 4); sum += __shfl_xor(sum, 8);
    __shared__ float tr[Rd];
    if (q == 0) tr[r] = sum;
    __syncthreads();
    if (tid < 32) {
        int j0 = tid * 2;
        uint v = 0;
        if ((j0 >> 4) == l)
            v = (uint)f2bf(s * tr[j0 & 15]) | ((uint)f2bf(s * tr[(j0 + 1) & 15]) << 16);
        ((uint*)(tmpde + (size_t)p * 64))[tid] = v;
    }
}

// ---------------- gate_up GEMM: A bf16 gload_lds, B fp32 reg-staged+cvt, dbuf LDS ----------------
// B-tile rows 0-63 = gate cols n0.., rows 64-127 = up cols 1024+n0..  fused silu -> act bf16
__global__ __launch_bounds__(256) void k_gemm_gu(
    const ushort* __restrict__ xb, const float* __restrict__ w13,
    const ushort* __restrict__ tmp1e, const ushort* __restrict__ gbbe,
    ushort* __restrict__ act, const int* __restrict__ sorted,
    const int* __restrict__ offs)
{
    __shared__ ushort As[2][128][32];
    __shared__ ushort Bs[2][128][32];
    const int tid = threadIdx.x, lane = tid & 63, wave = tid >> 6;
    const int wr = wave >> 1, wc = wave & 1;
    const int fr = lane & 15, fk = (lane >> 4) * 8;

    int off[Ed + 1];
    #pragma unroll
    for (int e = 0; e <= Ed; ++e) off[e] = offs[e];
    int mt[Ed]; int tot = 0;
    #pragma unroll
    for (int e = 0; e < Ed; ++e) {
        mt[e] = (off[e + 1] - off[e] + 127) / 128;
        tot += mt[e] * 16;
    }

    for (int tau = blockIdx.x; tau < tot; tau += gridDim.x) {
        int t = tau, e = 0;
        while (t >= mt[e] * 16) { t -= mt[e] * 16; ++e; }
        const int m0 = off[e] + (t >> 4) * 128;
        const int mend = off[e + 1];
        const int n0 = (t & 15) * 64;

        // A staging (gload_lds, 2 rounds): chunk c -> row c>>2, kchunk c&3
        const ushort *asrc[2], *aesrc[2], *besrc[2];
        #pragma unroll
        for (int r = 0; r < 2; ++r) {
            int c = r * 256 + tid;
            int row = c >> 2, kc = c & 3;
            int aIdx = m0 + row; if (aIdx > mend - 1) aIdx = mend - 1;
            int p = sorted[aIdx];
            asrc[r]  = xb + (size_t)(p >> 1) * 1024 + kc * 8;
            aesrc[r] = tmp1e + (size_t)p * 64 + kc * 8;
            int grow = (row < 64) ? (n0 + row) : (1024 + n0 + row - 64);
            besrc[r] = gbbe + ((size_t)e * Nd + grow) * 64 + kc * 8;
        }
        // B fp32 staging: row = tid>>1 (gate 0-63 / up 64-127), half = tid&1 -> 16 floats
        const int brow = tid >> 1, bhalf = tid & 1;
        const int bg_row = (brow < 64) ? (n0 + brow) : (1024 + n0 + brow - 64);
        const float* bsrc = w13 + ((size_t)e * Nd + bg_row) * 1024 + bhalf * 16;

        f32x4 ag[4][2] = {}, au[4][2] = {};
        auto step = [&](int buf) {
            bf16x8 af[4], bg[2], bu[2];
            #pragma unroll
            for (int mi = 0; mi < 4; ++mi)
                af[mi] = *(const bf16x8*)(&As[buf][wr * 64 + mi * 16 + fr][fk]);
            #pragma unroll
            for (int ni = 0; ni < 2; ++ni) {
                bg[ni] = *(const bf16x8*)(&Bs[buf][wc * 32 + ni * 16 + fr][fk]);
                bu[ni] = *(const bf16x8*)(&Bs[buf][64 + wc * 32 + ni * 16 + fr][fk]);
            }
            #pragma unroll
            for (int mi = 0; mi < 4; ++mi)
                #pragma unroll
                for (int ni = 0; ni < 2; ++ni) {
                    ag[mi][ni] = __builtin_amdgcn_mfma_f32_16x16x32_bf16(af[mi], bg[ni], ag[mi][ni], 0, 0, 0);
                    au[mi][ni] = __builtin_amdgcn_mfma_f32_16x16x32_bf16(af[mi], bu[ni], au[mi][ni], 0, 0, 0);
                }
        };

        // prologue: stage k0=0 into buffer 0
        #pragma unroll
        for (int r = 0; r < 2; ++r)
            GLOAD_LDS16(asrc[r], (char*)&As[0][0][0] + (r * 256 + wave * 64) * 16);
        {
            float4 y0 = *(const float4*)(bsrc);
            float4 y1 = *(const float4*)(bsrc + 4);
            float4 y2 = *(const float4*)(bsrc + 8);
            float4 y3 = *(const float4*)(bsrc + 12);
            *(bf16x8*)(&Bs[0][brow][bhalf * 16])     = pack8(y0, y1);
            *(bf16x8*)(&Bs[0][brow][bhalf * 16 + 8]) = pack8(y2, y3);
        }
        __syncthreads();

        int buf = 0;
        for (int k0 = 32; k0 < 1024; k0 += 32) {
            // issue next-step loads first (hide under MFMA)
            #pragma unroll
            for (int r = 0; r < 2; ++r)
                GLOAD_LDS16(asrc[r] + k0, (char*)&As[buf ^ 1][0][0] + (r * 256 + wave * 64) * 16);
            float4 y0 = *(const float4*)(bsrc + k0);
            float4 y1 = *(const float4*)(bsrc + k0 + 4);
            float4 y2 = *(const float4*)(bsrc + k0 + 8);
            float4 y3 = *(const float4*)(bsrc + k0 + 12);

            step(buf);

            *(bf16x8*)(&Bs[buf ^ 1][brow][bhalf * 16])     = pack8(y0, y1);
            *(bf16x8*)(&Bs[buf ^ 1][brow][bhalf * 16 + 8]) = pack8(y2, y3);
            __syncthreads();
            buf ^= 1;
        }
        step(buf);                    // k0 = 992 (buf == 1 after 31 flips)

        // LoRA-B ext: 2 K-steps over 64-wide slot space; es -> buffer es
        #pragma unroll
        for (int es = 0; es < 2; ++es) {
            #pragma unroll
            for (int r = 0; r < 2; ++r) {
                GLOAD_LDS16(aesrc[r] + es * 32, (char*)&As[es][0][0] + (r * 256 + wave * 64) * 16);
                GLOAD_LDS16(besrc[r] + es * 32, (char*)&Bs[es][0][0] + (r * 256 + wave * 64) * 16);
            }
            __syncthreads();
            step(es);
        }

        // epilogue: fused silu_and_mul -> act bf16
        const int rb = wr * 64 + (lane >> 4) * 4;
        #pragma unroll
        for (int mi = 0; mi < 4; ++mi) {
            #pragma unroll
            for (int j = 0; j < 4; ++j) {
                int sidx = m0 + rb + mi * 16 + j;
                if (sidx < mend) {
                    int p = sorted[sidx];
                    ushort* ar = act + (size_t)p * 1024 + n0 + wc * 32;
                    #pragma unroll
                    for (int ni = 0; ni < 2; ++ni) {
                        float g = ag[mi][ni][j], u = au[mi][ni][j];
                        float v = g / (1.f + __expf(-g)) * u;
                        ar[ni * 16 + fr] = f2bf(v);
                    }
                }
            }
        }
        __syncthreads();              // protect LDS before next tile's prologue
    }
}

// ---------------- down GEMM: A act bf16 gload_lds, B w2 fp32 reg-staged, atomic epilogue ----------------
__global__ __launch_bounds__(256) void k_gemm_dn(
    const ushort* __restrict__ act, const float* __restrict__ w2,
    const ushort* __restrict__ tmpde, const ushort* __restrict__ dbbe,
    const float* __restrict__ tw, float* __restrict__ out,
    const int* __restrict__ sorted, const int* __restrict__ offs)
{
    __shared__ ushort As[2][128][32];
    __shared__ ushort Bs[2][64][32];
    const int tid = threadIdx.x, lane = tid & 63, wave = tid >> 6;
    const int wr = wave >> 1, wc = wave & 1;
    const int fr = lane & 15, fk = (lane >> 4) * 8;

    int off[Ed + 1];
    #pragma unroll
    for (int e = 0; e <= Ed; ++e) off[e] = offs[e];
    int mt[Ed]; int tot = 0;
    #pragma unroll
    for (int e = 0; e < Ed; ++e) {
        mt[e] = (off[e + 1] - off[e] + 127) / 128;
        tot += mt[e] * 16;
    }

    for (int tau = blockIdx.x; tau < tot; tau += gridDim.x) {
        int t = tau, e = 0;
        while (t >= mt[e] * 16) { t -= mt[e] * 16; ++e; }
        const int m0 = off[e] + (t >> 4) * 128;
        const int mend = off[e + 1];
        const int n0 = (t & 15) * 64;

        const ushort *asrc[2], *aesrc[2], *besrc;
        #pragma unroll
        for (int r = 0; r < 2; ++r) {
            int c = r * 256 + tid;
            int row = c >> 2, kc = c & 3;
            int aIdx = m0 + row; if (aIdx > mend - 1) aIdx = mend - 1;
            int p = sorted[aIdx];
            asrc[r]  = act + (size_t)p * 1024 + kc * 8;
            aesrc[r] = tmpde + (size_t)p * 64 + kc * 8;
        }
        besrc = dbbe + ((size_t)e * Hd + n0 + (tid >> 2)) * 64 + (tid & 3) * 8;
        // B fp32: row = tid>>2 (64 rows), q = tid&3 -> 8 floats
        const int brow = tid >> 2, bq = tid & 3;
        const float* bsrc = w2 + ((size_t)e * Hd + n0 + brow) * 1024 + bq * 8;

        f32x4 acc[4][2] = {};
        auto step = [&](int buf) {
            bf16x8 af[4], bv[2];
            #pragma unroll
            for (int mi = 0; mi < 4; ++mi)
                af[mi] = *(const bf16x8*)(&As[buf][wr * 64 + mi * 16 + fr][fk]);
            #pragma unroll
            for (int ni = 0; ni < 2; ++ni)
                bv[ni] = *(const bf16x8*)(&Bs[buf][wc * 32 + ni * 16 + fr][fk]);
            #pragma unroll
            for (int mi = 0; mi < 4; ++mi)
                #pragma unroll
                for (int ni = 0; ni < 2; ++ni)
                    acc[mi][ni] = __builtin_amdgcn_mfma_f32_16x16x32_bf16(af[mi], bv[ni], acc[mi][ni], 0, 0, 0);
        };

        #pragma unroll
        for (int r = 0; r < 2; ++r)
            GLOAD_LDS16(asrc[r], (char*)&As[0][0][0] + (r * 256 + wave * 64) * 16);
        {
            float4 y0 = *(const float4*)(bsrc);
            float4 y1 = *(const float4*)(bsrc + 4);
            *(bf16x8*)(&Bs[0][brow][bq * 8]) = pack8(y0, y1);
        }
        __syncthreads();

        int buf = 0;
        for (int k0 = 32; k0 < 1024; k0 += 32) {
            #pragma unroll
            for (int r = 0; r < 2; ++r)
                GLOAD_LDS16(asrc[r] + k0, (char*)&As[buf ^ 1][0][0] + (r * 256 + wave * 64) * 16);
            float4 y0 = *(const float4*)(bsrc + k0);
            float4 y1 = *(const float4*)(bsrc + k0 + 4);

            step(buf);

            *(bf16x8*)(&Bs[buf ^ 1][brow][bq * 8]) = pack8(y0, y1);
            __syncthreads();
            buf ^= 1;
        }
        step(buf);

        #pragma unroll
        for (int es = 0; es < 2; ++es) {
            #pragma unroll
            for (int r = 0; r < 2; ++r)
                GLOAD_LDS16(aesrc[r] + es * 32, (char*)&As[es][0][0] + (r * 256 + wave * 64) * 16);
            GLOAD_LDS16(besrc + es * 32, (char*)&Bs[es][0][0] + (wave * 64) * 16);
            __syncthreads();
            step(es);
        }

        const int rb = wr * 64 + (lane >> 4) * 4;
        #pragma unroll
        for (int mi = 0; mi < 4; ++mi) {
            #pragma unroll
            for (int j = 0; j < 4; ++j) {
                int sidx = m0 + rb + mi * 16 + j;
                if (sidx < mend) {
                    int p = sorted[sidx];
                    float w = tw[p];
                    float* orow = out + (size_t)(p >> 1) * 1024 + n0 + wc * 32;
                    #pragma unroll
                    for (int ni = 0; ni < 2; ++ni)
                        atomicAdd(&orow[ni * 16 + fr], w * acc[mi][ni][j]);
                }
            }
        }
        __syncthreads();
    }
}

extern "C" void kernel_launch(void* const* d_in, const int* in_sizes, int n_in,
                              void* d_out, int out_size, void* d_ws, size_t ws_size,
                              hipStream_t stream) {
    const float* hid  = (const float*)d_in[0];
    const float* tw   = (const float*)d_in[1];
    const float* w13  = (const float*)d_in[2];
    const float* w2   = (const float*)d_in[3];
    const float* ga   = (const float*)d_in[4];
    const float* gb   = (const float*)d_in[5];
    const float* da   = (const float*)d_in[6];
    const float* db   = (const float*)d_in[7];
    const float* sc   = (const float*)d_in[8];
    const int*   tids = (const int*)d_in[9];
    const int*   lidx = (const int*)d_in[10];
    float* out = (float*)d_out;

    char* ws = (char*)d_ws;
    ushort* xb     = (ushort*)(ws);                          // 2 MB
    ushort* gbbe   = (ushort*)(ws + (2ull << 20));           // 2 MB
    ushort* dbbe   = (ushort*)(ws + (4ull << 20));           // 1 MB
    ushort* tmp1e  = (ushort*)(ws + (5ull << 20));           // 256 KB
    ushort* tmpde  = (ushort*)(ws + (5ull << 20) + (256u << 10)); // 256 KB
    ushort* act    = (ushort*)(ws + (6ull << 20));           // 4 MB
    int*    sorted = (int*)(ws + (10ull << 20));             // 8 KB
    int*    offs   = (int*)(ws + (10ull << 20) + TKd * 4);   // 36 B

    k_prep<<<PREP_BLOCKS, 256, 0, stream>>>(hid, gb, db, ga, sc, tids, lidx,
                                            xb, gbbe, dbbe, tmp1e, out, sorted, offs);
    k_gemm_gu<<<512, 256, 0, stream>>>(xb, w13, tmp1e, gbbe, act, sorted, offs);
    k_tmp_dn<<<TKd, 256, 0, stream>>>(act, da, sc, tids, lidx, tmpde);
    k_gemm_dn<<<512, 256, 0, stream>>>(act, w2, tmpde, dbbe, tw, out, sorted, offs);
}